// Round 1
// baseline (317.886 us; speedup 1.0000x reference)
//
#include <hip/hip_runtime.h>
#include <hip/hip_bf16.h>

#define BQ 2
#define DIMC 192
#define DINNER 384
#define LQ 4096
#define NST 16
#define XDBLP 48
#define NCHUNK 128
#define CS 32   // LQ / NCHUNK

// ---------------- K0: transpose weights (W_x -> 384x48 padded, W_out -> 384x192) ----
__global__ void k0_transpose(const float* __restrict__ Wx, const float* __restrict__ Wout,
                             float* __restrict__ WxT, float* __restrict__ WoutT) {
    int t = blockIdx.x * 256 + threadIdx.x;
    if (t < DINNER * XDBLP) {
        int d = t / XDBLP, k = t % XDBLP;
        WxT[t] = (k < 44) ? Wx[k * DINNER + d] : 0.f;
    }
    if (t < DINNER * DIMC) {
        int d = t / DIMC, c = t % DIMC;
        WoutT[t] = Wout[c * DINNER + d];
    }
}

// ---------------- K1: xz = xf @ W_in ; split into x_in / z --------------------------
// grid (128 lblk, 8 mblk, 2 b), block 256.  Tile: 64 l x 96 m, thread = (l, 24 m).
__global__ __launch_bounds__(256) void k1_inproj(const float* __restrict__ x,
                                                 const float* __restrict__ W_in,
                                                 float* __restrict__ x_in,
                                                 float* __restrict__ zbuf) {
    __shared__ float xs[DIMC * 64];   // 48 KB, [c][l]
    int b = blockIdx.z, lb = blockIdx.x, mb = blockIdx.y;
    int t = threadIdx.x;
    int l0 = lb * 64;
    const float* xb = x + (size_t)b * DIMC * LQ;
    #pragma unroll
    for (int it = 0; it < 48; ++it) {
        int idx = it * 256 + t;
        int c = idx >> 6, l = idx & 63;
        xs[idx] = xb[(size_t)c * LQ + l0 + l];   // coalesced in l
    }
    __syncthreads();
    int l = t & 63;
    int mg = __builtin_amdgcn_readfirstlane(t >> 6);   // wave-uniform col group
    int m0 = mb * 96 + mg * 24;
    float acc[24];
    #pragma unroll
    for (int i = 0; i < 24; ++i) acc[i] = 0.f;
    for (int c = 0; c < DIMC; ++c) {
        float xv = xs[c * 64 + l];
        const float* Wr = W_in + (size_t)c * 768 + m0;  // uniform -> s_load
        #pragma unroll
        for (int i = 0; i < 24; ++i) acc[i] = fmaf(xv, Wr[i], acc[i]);
    }
    size_t row = (size_t)(b * LQ + l0 + l) * DINNER;
    float* dst = (m0 < DINNER) ? (x_in + row + m0) : (zbuf + row + (m0 - DINNER));
    #pragma unroll
    for (int i = 0; i < 24; i += 4)
        *(float4*)(dst + i) = make_float4(acc[i], acc[i+1], acc[i+2], acc[i+3]);
}

// ---------------- K2: causal depthwise conv(4) + silu -------------------------------
__global__ void k2_conv(const float* __restrict__ x_in, const float* __restrict__ conv_w,
                        const float* __restrict__ conv_b, float* __restrict__ x_conv) {
    size_t tid = (size_t)blockIdx.x * 256 + threadIdx.x;   // over B*L*384
    int d = (int)(tid % DINNER);
    int l = (int)((tid / DINNER) % LQ);
    float4 w = *(const float4*)(conv_w + d * 4);
    float acc = conv_b[d];
    float v;
    v = (l >= 3) ? x_in[tid - 3 * DINNER] : 0.f; acc = fmaf(w.x, v, acc);
    v = (l >= 2) ? x_in[tid - 2 * DINNER] : 0.f; acc = fmaf(w.y, v, acc);
    v = (l >= 1) ? x_in[tid - 1 * DINNER] : 0.f; acc = fmaf(w.z, v, acc);
    v = x_in[tid];                               acc = fmaf(w.w, v, acc);
    x_conv[tid] = acc / (1.f + __expf(-acc));    // silu
}

// ---------------- K3: x_dbl[b,l,k] = sum_d x_conv[b,l,d] * W_x[k,d] -----------------
// grid (128 lblk, 2 b), block 256. Tile 64 l x 48 k (44 real), thread = (l, 12 k).
__global__ __launch_bounds__(256) void k3_xdbl(const float* __restrict__ x_conv,
                                               const float* __restrict__ WxT,
                                               float* __restrict__ x_dbl) {
    __shared__ float xs[96 * 65];   // [d][l] padded
    int b = blockIdx.y, lb = blockIdx.x;
    int t = threadIdx.x;
    int l0 = lb * 64;
    int l = t & 63;
    int kg = __builtin_amdgcn_readfirstlane(t >> 6);
    int k0 = kg * 12;
    float acc[12];
    #pragma unroll
    for (int i = 0; i < 12; ++i) acc[i] = 0.f;
    for (int db = 0; db < 4; ++db) {
        __syncthreads();
        #pragma unroll
        for (int it = 0; it < 24; ++it) {
            int idx = it * 256 + t;        // 6144 = 96*64
            int dd = idx % 96, ll = idx / 96;
            xs[dd * 65 + ll] = x_conv[(size_t)(b * LQ + l0 + ll) * DINNER + db * 96 + dd];
        }
        __syncthreads();
        for (int dd = 0; dd < 96; ++dd) {
            float xv = xs[dd * 65 + l];
            const float* Wr = WxT + (size_t)(db * 96 + dd) * XDBLP + k0;  // uniform
            #pragma unroll
            for (int i = 0; i < 12; ++i) acc[i] = fmaf(xv, Wr[i], acc[i]);
        }
    }
    float* dst = x_dbl + (size_t)(b * LQ + l0 + l) * XDBLP + k0;
    #pragma unroll
    for (int i = 0; i < 12; i += 4)
        *(float4*)(dst + i) = make_float4(acc[i], acc[i+1], acc[i+2], acc[i+3]);
}

// ---------------- K4: delta = softplus(dt @ W_dt^T + 2*b_dt) -------------------------
__global__ void k4_delta(const float* __restrict__ x_dbl, const float* __restrict__ W_dt,
                         const float* __restrict__ b_dt, float* __restrict__ delta) {
    size_t tid = (size_t)blockIdx.x * 256 + threadIdx.x;   // over B*L*384
    int d = (int)(tid % DINNER);
    size_t bl = tid / DINNER;
    const float4* dt4 = (const float4*)(x_dbl + bl * XDBLP);
    const float4* w4  = (const float4*)(W_dt + d * 12);
    float4 t0 = dt4[0], t1 = dt4[1], t2 = dt4[2];
    float4 w0 = w4[0],  w1 = w4[1],  w2 = w4[2];
    float acc = 2.f * b_dt[d];
    acc = fmaf(t0.x, w0.x, acc); acc = fmaf(t0.y, w0.y, acc);
    acc = fmaf(t0.z, w0.z, acc); acc = fmaf(t0.w, w0.w, acc);
    acc = fmaf(t1.x, w1.x, acc); acc = fmaf(t1.y, w1.y, acc);
    acc = fmaf(t1.z, w1.z, acc); acc = fmaf(t1.w, w1.w, acc);
    acc = fmaf(t2.x, w2.x, acc); acc = fmaf(t2.y, w2.y, acc);
    acc = fmaf(t2.z, w2.z, acc); acc = fmaf(t2.w, w2.w, acc);
    // softplus, numerically stable
    delta[tid] = fmaxf(acc, 0.f) + log1pf(__expf(-fabsf(acc)));
}

// ---------------- K5: scan pass A — per-chunk local scan, emit h_end + sum(delta) ----
__global__ __launch_bounds__(DINNER) void k5_scanA(const float* __restrict__ delta,
                                                   const float* __restrict__ x_conv,
                                                   const float* __restrict__ x_dbl,
                                                   const float* __restrict__ A_log,
                                                   float* __restrict__ hend,
                                                   float* __restrict__ sumdelta) {
    __shared__ float bs[CS * NST];
    int b = blockIdx.y, ch = blockIdx.x;
    int l0 = ch * CS;
    int t = threadIdx.x;   // = d
    for (int idx = t; idx < CS * NST; idx += DINNER) {
        int n = idx & 15, ll = idx >> 4;
        bs[idx] = x_dbl[(size_t)(b * LQ + l0 + ll) * XDBLP + 12 + n];
    }
    __syncthreads();
    float A[NST];
    #pragma unroll
    for (int n = 0; n < NST; ++n) A[n] = -__expf(A_log[t * NST + n]);
    float h[NST];
    #pragma unroll
    for (int n = 0; n < NST; ++n) h[n] = 0.f;
    float sd = 0.f;
    for (int ll = 0; ll < CS; ++ll) {
        size_t gi = (size_t)(b * LQ + l0 + ll) * DINNER + t;
        float dl = delta[gi];
        float u  = x_conv[gi];
        float du = dl * u;
        sd += dl;
        #pragma unroll
        for (int n = 0; n < NST; ++n) {
            float dA = __expf(dl * A[n]);
            h[n] = fmaf(dA, h[n], du * bs[ll * NST + n]);
        }
    }
    size_t base = (size_t)((b * NCHUNK + ch) * DINNER + t) * NST;
    #pragma unroll
    for (int n = 0; n < NST; n += 4)
        *(float4*)(hend + base + n) = make_float4(h[n], h[n+1], h[n+2], h[n+3]);
    sumdelta[(b * NCHUNK + ch) * DINNER + t] = sd;
}

// ---------------- K6: sequential chunk combine -> h_in per chunk ---------------------
__global__ void k6_combine(const float* __restrict__ A_log, const float* __restrict__ sumdelta,
                           const float* __restrict__ hend, float* __restrict__ hin) {
    int t = blockIdx.x * 256 + threadIdx.x;   // B*384*16 = 12288
    int n = t & 15, d = (t >> 4) % DINNER, b = t / (DINNER * NST);
    float A = -__expf(A_log[d * NST + n]);
    float carry = 0.f;
    for (int c = 0; c < NCHUNK; ++c) {
        size_t idx = (size_t)((b * NCHUNK + c) * DINNER + d) * NST + n;
        hin[idx] = carry;
        carry = fmaf(__expf(A * sumdelta[(b * NCHUNK + c) * DINNER + d]), carry, hend[idx]);
    }
}

// ---------------- K7: scan pass C — real scan with h_in, emit gated y ----------------
__global__ __launch_bounds__(DINNER) void k7_scanC(const float* __restrict__ delta,
                                                   const float* __restrict__ x_conv,
                                                   const float* __restrict__ x_dbl,
                                                   const float* __restrict__ A_log,
                                                   const float* __restrict__ hin,
                                                   const float* __restrict__ Dp,
                                                   const float* __restrict__ zbuf,
                                                   float* __restrict__ y) {
    __shared__ float bs[CS * NST], cs2[CS * NST];
    int b = blockIdx.y, ch = blockIdx.x;
    int l0 = ch * CS;
    int t = threadIdx.x;
    for (int idx = t; idx < CS * NST; idx += DINNER) {
        int n = idx & 15, ll = idx >> 4;
        size_t r = (size_t)(b * LQ + l0 + ll) * XDBLP;
        bs[idx]  = x_dbl[r + 12 + n];
        cs2[idx] = x_dbl[r + 28 + n];
    }
    __syncthreads();
    float A[NST];
    #pragma unroll
    for (int n = 0; n < NST; ++n) A[n] = -__expf(A_log[t * NST + n]);
    float h[NST];
    size_t hbase = (size_t)((b * NCHUNK + ch) * DINNER + t) * NST;
    #pragma unroll
    for (int n = 0; n < NST; n += 4) {
        float4 v = *(const float4*)(hin + hbase + n);
        h[n] = v.x; h[n+1] = v.y; h[n+2] = v.z; h[n+3] = v.w;
    }
    float Dd = Dp[t];
    for (int ll = 0; ll < CS; ++ll) {
        size_t gi = (size_t)(b * LQ + l0 + ll) * DINNER + t;
        float dl = delta[gi];
        float u  = x_conv[gi];
        float z  = zbuf[gi];
        float du = dl * u;
        float yv = 0.f;
        #pragma unroll
        for (int n = 0; n < NST; ++n) {
            float dA = __expf(dl * A[n]);
            h[n] = fmaf(dA, h[n], du * bs[ll * NST + n]);
            yv = fmaf(h[n], cs2[ll * NST + n], yv);
        }
        yv = fmaf(u, Dd, yv);
        float sig = 1.f / (1.f + __expf(-z));
        y[gi] = yv * (z * sig);
    }
}

// ---------------- K8: out[b,c,l] = sum_d y[b,l,d] * W_out[c,d] -----------------------
// grid (128 lblk, 2 cblk, 2 b), block 256. Tile 64 l x 96 c, thread = (l, 24 c).
__global__ __launch_bounds__(256) void k8_out(const float* __restrict__ y,
                                              const float* __restrict__ WoutT,
                                              float* __restrict__ out) {
    __shared__ float ys[128 * 65];   // [d][l] padded
    int b = blockIdx.z, cb = blockIdx.y, lb = blockIdx.x;
    int l0 = lb * 64;
    int t = threadIdx.x;
    int l = t & 63;
    int cg = __builtin_amdgcn_readfirstlane(t >> 6);
    int c0 = cb * 96 + cg * 24;
    float acc[24];
    #pragma unroll
    for (int i = 0; i < 24; ++i) acc[i] = 0.f;
    for (int db = 0; db < 3; ++db) {
        __syncthreads();
        #pragma unroll
        for (int it = 0; it < 32; ++it) {
            int idx = it * 256 + t;        // 8192 = 128*64
            int dd = idx & 127, ll = idx >> 7;
            ys[dd * 65 + ll] = y[(size_t)(b * LQ + l0 + ll) * DINNER + db * 128 + dd];
        }
        __syncthreads();
        for (int dd = 0; dd < 128; ++dd) {
            float yv = ys[dd * 65 + l];
            const float* Wr = WoutT + (size_t)(db * 128 + dd) * DIMC + c0;  // uniform
            #pragma unroll
            for (int i = 0; i < 24; ++i) acc[i] = fmaf(yv, Wr[i], acc[i]);
        }
    }
    size_t ob = ((size_t)b * DIMC + c0) * LQ + l0 + l;
    #pragma unroll
    for (int i = 0; i < 24; ++i) out[ob + (size_t)i * LQ] = acc[i];
}

extern "C" void kernel_launch(void* const* d_in, const int* in_sizes, int n_in,
                              void* d_out, int out_size, void* d_ws, size_t ws_size,
                              hipStream_t stream) {
    const float* x      = (const float*)d_in[0];
    const float* W_in   = (const float*)d_in[1];
    const float* conv_w = (const float*)d_in[2];
    const float* conv_b = (const float*)d_in[3];
    const float* W_x    = (const float*)d_in[4];
    const float* W_dt   = (const float*)d_in[5];
    const float* b_dt   = (const float*)d_in[6];
    const float* A_log  = (const float*)d_in[7];
    const float* Dp     = (const float*)d_in[8];
    const float* W_out  = (const float*)d_in[9];
    float* out = (float*)d_out;

    float* w = (float*)d_ws;
    float* x_in   = w; w += (size_t)BQ * LQ * DINNER;   // 3,145,728
    float* zbuf   = w; w += (size_t)BQ * LQ * DINNER;
    float* x_conv = w; w += (size_t)BQ * LQ * DINNER;
    float* x_dbl  = w; w += (size_t)BQ * LQ * XDBLP;    //   393,216
    float* delta  = w; w += (size_t)BQ * LQ * DINNER;
    float* ybuf   = w; w += (size_t)BQ * LQ * DINNER;
    float* hend   = w; w += (size_t)BQ * NCHUNK * DINNER * NST;  // 1,572,864
    float* hin    = w; w += (size_t)BQ * NCHUNK * DINNER * NST;
    float* sumd   = w; w += (size_t)BQ * NCHUNK * DINNER;        //    98,304
    float* WxT    = w; w += (size_t)DINNER * XDBLP;
    float* WoutT  = w; w += (size_t)DINNER * DIMC;

    k0_transpose<<<288, 256, 0, stream>>>(W_x, W_out, WxT, WoutT);
    k1_inproj<<<dim3(LQ / 64, 8, BQ), 256, 0, stream>>>(x, W_in, x_in, zbuf);
    k2_conv<<<(BQ * LQ * DINNER) / 256, 256, 0, stream>>>(x_in, conv_w, conv_b, x_conv);
    k3_xdbl<<<dim3(LQ / 64, BQ), 256, 0, stream>>>(x_conv, WxT, x_dbl);
    k4_delta<<<(BQ * LQ * DINNER) / 256, 256, 0, stream>>>(x_dbl, W_dt, b_dt, delta);
    k5_scanA<<<dim3(NCHUNK, BQ), DINNER, 0, stream>>>(delta, x_conv, x_dbl, A_log, hend, sumd);
    k6_combine<<<(BQ * DINNER * NST) / 256, 256, 0, stream>>>(A_log, sumd, hend, hin);
    k7_scanC<<<dim3(NCHUNK, BQ), DINNER, 0, stream>>>(delta, x_conv, x_dbl, A_log, hin, Dp, zbuf, ybuf);
    k8_out<<<dim3(LQ / 64, 2, BQ), 256, 0, stream>>>(ybuf, WoutT, out);
}

// Round 2
// 258.339 us; speedup vs baseline: 1.2305x; 1.2305x over previous
//
#include <hip/hip_runtime.h>

#define BQ 2
#define DIMC 192
#define DINNER 384
#define LQ 4096
#define NST 16
#define XDBLP 48
#define NCHUNK 256
#define CS 16   // LQ / NCHUNK

// ---------------- K0: transpose weights (W_x -> 384x48 padded, W_out -> 384x192) ----
__global__ void k0_transpose(const float* __restrict__ Wx, const float* __restrict__ Wout,
                             float* __restrict__ WxT, float* __restrict__ WoutT) {
    int t = blockIdx.x * 256 + threadIdx.x;
    if (t < DINNER * XDBLP) {
        int d = t / XDBLP, k = t % XDBLP;
        WxT[t] = (k < 44) ? Wx[k * DINNER + d] : 0.f;
    }
    if (t < DINNER * DIMC) {
        int d = t / DIMC, c = t % DIMC;
        WoutT[t] = Wout[c * DINNER + d];
    }
}

// ---------------- K1: xz = xf @ W_in  (register-tiled, no LDS) ----------------------
// grid (32 lb, 12 mb, 2 b), block 256 = 4 waves. Thread: 2 l (lane, lane+64) x 16 m.
// Weights are wave-uniform rows -> s_load (lgkmcnt only); x loads coalesced (vmcnt).
__global__ __launch_bounds__(256) void k1_inproj(const float* __restrict__ x,
                                                 const float* __restrict__ W_in,
                                                 float* __restrict__ x_in,
                                                 float* __restrict__ zbuf) {
    int b = blockIdx.z, lb = blockIdx.x, mb = blockIdx.y;
    int t = threadIdx.x;
    int lane = t & 63;
    int wg = __builtin_amdgcn_readfirstlane(t >> 6);
    int m0 = mb * 64 + wg * 16;
    int l0 = lb * 128;
    const float* xb = x + (size_t)b * DIMC * LQ + l0 + lane;
    float acc0[16], acc1[16];
    #pragma unroll
    for (int i = 0; i < 16; ++i) { acc0[i] = 0.f; acc1[i] = 0.f; }
    #pragma unroll 4
    for (int c = 0; c < DIMC; ++c) {
        float xv0 = xb[(size_t)c * LQ];
        float xv1 = xb[(size_t)c * LQ + 64];
        const float* Wr = W_in + (size_t)c * 768 + m0;   // uniform -> s_load
        #pragma unroll
        for (int i = 0; i < 16; ++i) {
            float w = Wr[i];
            acc0[i] = fmaf(xv0, w, acc0[i]);
            acc1[i] = fmaf(xv1, w, acc1[i]);
        }
    }
    size_t row0 = (size_t)(b * LQ + l0 + lane) * DINNER;
    size_t row1 = row0 + (size_t)64 * DINNER;
    float* dst0;
    float* dst1;
    if (mb < 6) { dst0 = x_in + row0 + m0; dst1 = x_in + row1 + m0; }
    else        { dst0 = zbuf + row0 + m0 - DINNER; dst1 = zbuf + row1 + m0 - DINNER; }
    #pragma unroll
    for (int i = 0; i < 16; i += 4) {
        *(float4*)(dst0 + i) = make_float4(acc0[i], acc0[i+1], acc0[i+2], acc0[i+3]);
        *(float4*)(dst1 + i) = make_float4(acc1[i], acc1[i+1], acc1[i+2], acc1[i+3]);
    }
}

// ---------------- K2: causal conv(4)+silu -> x_conv [b,l,d] AND x_convT [b,d,l] -----
// grid (128 lb, 2 b), block 512. 32-l tile, LDS transpose for the T layout.
__global__ __launch_bounds__(512) void k2_conv(const float* __restrict__ x_in,
                                               const float* __restrict__ conv_w,
                                               const float* __restrict__ conv_b,
                                               float* __restrict__ x_conv,
                                               float* __restrict__ x_convT) {
    __shared__ float cs[32 * DINNER];   // 48 KB
    int b = blockIdx.y, lb = blockIdx.x;
    int l0 = lb * 32;
    int t = threadIdx.x;
    #pragma unroll
    for (int it = 0; it < 24; ++it) {
        int e = it * 512 + t;             // 12288 = 32*384
        int ll = e / DINNER, d = e % DINNER;
        int l = l0 + ll;
        size_t gi = (size_t)(b * LQ + l) * DINNER + d;
        float4 w = *(const float4*)(conv_w + d * 4);
        float acc = conv_b[d];
        float v;
        v = (l >= 3) ? x_in[gi - 3 * DINNER] : 0.f; acc = fmaf(w.x, v, acc);
        v = (l >= 2) ? x_in[gi - 2 * DINNER] : 0.f; acc = fmaf(w.y, v, acc);
        v = (l >= 1) ? x_in[gi - 1 * DINNER] : 0.f; acc = fmaf(w.z, v, acc);
        v = x_in[gi];                               acc = fmaf(w.w, v, acc);
        float r = acc / (1.f + __expf(-acc));
        x_conv[gi] = r;
        cs[e] = r;
    }
    __syncthreads();
    if (t < DINNER) {
        float* dst = x_convT + ((size_t)(b * DINNER) + t) * LQ + l0;
        #pragma unroll
        for (int q = 0; q < 32; q += 4) {
            float4 v = make_float4(cs[(q+0) * DINNER + t], cs[(q+1) * DINNER + t],
                                   cs[(q+2) * DINNER + t], cs[(q+3) * DINNER + t]);
            *(float4*)(dst + q) = v;
        }
    }
}

// ---------------- K3: x_dbl partials (split-K=4): p[ds][b,l,48] ---------------------
// grid (64 lb, 4 ds, 2 b), block 256 = 64 l-lanes x 4 kg(12 k each).
__global__ __launch_bounds__(256) void k3_xdbl(const float* __restrict__ x_convT,
                                               const float* __restrict__ WxT,
                                               float* __restrict__ xdp) {
    int b = blockIdx.z, ds = blockIdx.y, lb = blockIdx.x;
    int t = threadIdx.x;
    int lane = t & 63;
    int kg = __builtin_amdgcn_readfirstlane(t >> 6);
    int k0 = kg * 12;
    int l = lb * 64 + lane;
    const float* src = x_convT + (size_t)(b * DINNER + ds * 96) * LQ + l;
    float acc[12];
    #pragma unroll
    for (int i = 0; i < 12; ++i) acc[i] = 0.f;
    #pragma unroll 4
    for (int d = 0; d < 96; ++d) {
        float xv = src[(size_t)d * LQ];
        const float* Wr = WxT + (size_t)(ds * 96 + d) * XDBLP + k0;  // uniform
        #pragma unroll
        for (int i = 0; i < 12; ++i) acc[i] = fmaf(xv, Wr[i], acc[i]);
    }
    float* dst = xdp + (size_t)ds * (BQ * LQ * XDBLP) + (size_t)(b * LQ + l) * XDBLP + k0;
    #pragma unroll
    for (int i = 0; i < 12; i += 4)
        *(float4*)(dst + i) = make_float4(acc[i], acc[i+1], acc[i+2], acc[i+3]);
}

// ---------------- K5: scan pass A — local chunk scan, inline delta ------------------
// grid (256 ch, 2 b), block 384 (thread = d). hend[b][d][ch][n], sumd[b][d][ch].
__global__ __launch_bounds__(DINNER) void k5_scanA(const float* __restrict__ x_conv,
                                                   const float* __restrict__ xdp,
                                                   const float* __restrict__ W_dt,
                                                   const float* __restrict__ b_dt,
                                                   const float* __restrict__ A_log,
                                                   float* __restrict__ hend,
                                                   float* __restrict__ sumd) {
    __shared__ float xd[CS * XDBLP];   // 3 KB: dt|B|C rows for this chunk
    int b = blockIdx.y, ch = blockIdx.x;
    int l0 = ch * CS;
    int t = threadIdx.x;
    const size_t PD = (size_t)BQ * LQ * XDBLP;
    size_t base = (size_t)(b * LQ + l0) * XDBLP;
    for (int idx = t; idx < CS * XDBLP; idx += DINNER)
        xd[idx] = xdp[base + idx] + xdp[PD + base + idx]
                + xdp[2 * PD + base + idx] + xdp[3 * PD + base + idx];
    float wdt[12];
    #pragma unroll
    for (int r = 0; r < 12; r += 4) {
        float4 v = *(const float4*)(W_dt + t * 12 + r);
        wdt[r] = v.x; wdt[r+1] = v.y; wdt[r+2] = v.z; wdt[r+3] = v.w;
    }
    float bdt2 = 2.f * b_dt[t];
    float A[NST];
    #pragma unroll
    for (int n = 0; n < NST; ++n) A[n] = -__expf(A_log[t * NST + n]);
    __syncthreads();
    float h[NST];
    #pragma unroll
    for (int n = 0; n < NST; ++n) h[n] = 0.f;
    float sd = 0.f;
    for (int ll = 0; ll < CS; ++ll) {
        float u = x_conv[(size_t)(b * LQ + l0 + ll) * DINNER + t];
        float dr = bdt2;
        #pragma unroll
        for (int r = 0; r < 12; ++r) dr = fmaf(xd[ll * XDBLP + r], wdt[r], dr);
        float dl = fmaxf(dr, 0.f) + log1pf(__expf(-fabsf(dr)));   // softplus
        sd += dl;
        float du = dl * u;
        #pragma unroll
        for (int n = 0; n < NST; ++n)
            h[n] = fmaf(__expf(dl * A[n]), h[n], du * xd[ll * XDBLP + 12 + n]);
    }
    size_t hb = ((size_t)(b * DINNER + t) * NCHUNK + ch) * NST;
    #pragma unroll
    for (int n = 0; n < NST; n += 4)
        *(float4*)(hend + hb + n) = make_float4(h[n], h[n+1], h[n+2], h[n+3]);
    sumd[(size_t)(b * DINNER + t) * NCHUNK + ch] = sd;
}

// ---------------- K6: chunk-carry combine, parallel per (b,d) -----------------------
// grid (384 d, 2 b), block 64 = 16 n x 4 chunk-groups of 64.
__global__ __launch_bounds__(64) void k6_combine(const float* __restrict__ A_log,
                                                 const float* __restrict__ sumd,
                                                 const float* __restrict__ hend,
                                                 float* __restrict__ hin) {
    __shared__ float As[4][NST], Bs[4][NST];
    int d = blockIdx.x, b = blockIdx.y;
    int t = threadIdx.x;
    int n = t & 15, g = t >> 4;
    float A = -__expf(A_log[d * NST + n]);
    size_t sb = (size_t)(b * DINNER + d) * NCHUNK;
    size_t hb = sb * NST;
    float ca = 1.f, cb = 0.f;
    for (int i = 0; i < 64; ++i) {
        int ch = g * 64 + i;
        float a = __expf(A * sumd[sb + ch]);
        float bh = hend[hb + (size_t)ch * NST + n];
        ca *= a;
        cb = fmaf(a, cb, bh);
    }
    As[g][n] = ca; Bs[g][n] = cb;
    __syncthreads();
    float carry = 0.f;                       // h0 = 0
    for (int j = 0; j < g; ++j) carry = fmaf(As[j][n], carry, Bs[j][n]);
    for (int i = 0; i < 64; ++i) {
        int ch = g * 64 + i;
        hin[hb + (size_t)ch * NST + n] = carry;
        float a = __expf(A * sumd[sb + ch]);
        float bh = hend[hb + (size_t)ch * NST + n];
        carry = fmaf(a, carry, bh);
    }
}

// ---------------- K7: scan pass C — inline delta, gate, emit yT[b,d,l] --------------
// grid (256 ch, 2 b), block 384.
__global__ __launch_bounds__(DINNER) void k7_scanC(const float* __restrict__ x_conv,
                                                   const float* __restrict__ xdp,
                                                   const float* __restrict__ W_dt,
                                                   const float* __restrict__ b_dt,
                                                   const float* __restrict__ A_log,
                                                   const float* __restrict__ hin,
                                                   const float* __restrict__ Dp,
                                                   const float* __restrict__ zbuf,
                                                   float* __restrict__ yT) {
    __shared__ float xd[CS * XDBLP];       // 3 KB
    __shared__ float ys[CS * DINNER];      // 24.6 KB
    int b = blockIdx.y, ch = blockIdx.x;
    int l0 = ch * CS;
    int t = threadIdx.x;
    const size_t PD = (size_t)BQ * LQ * XDBLP;
    size_t base = (size_t)(b * LQ + l0) * XDBLP;
    for (int idx = t; idx < CS * XDBLP; idx += DINNER)
        xd[idx] = xdp[base + idx] + xdp[PD + base + idx]
                + xdp[2 * PD + base + idx] + xdp[3 * PD + base + idx];
    float wdt[12];
    #pragma unroll
    for (int r = 0; r < 12; r += 4) {
        float4 v = *(const float4*)(W_dt + t * 12 + r);
        wdt[r] = v.x; wdt[r+1] = v.y; wdt[r+2] = v.z; wdt[r+3] = v.w;
    }
    float bdt2 = 2.f * b_dt[t];
    float A[NST];
    #pragma unroll
    for (int n = 0; n < NST; ++n) A[n] = -__expf(A_log[t * NST + n]);
    float h[NST];
    size_t hb = ((size_t)(b * DINNER + t) * NCHUNK + ch) * NST;
    #pragma unroll
    for (int n = 0; n < NST; n += 4) {
        float4 v = *(const float4*)(hin + hb + n);
        h[n] = v.x; h[n+1] = v.y; h[n+2] = v.z; h[n+3] = v.w;
    }
    float Dd = Dp[t];
    __syncthreads();
    for (int ll = 0; ll < CS; ++ll) {
        size_t gi = (size_t)(b * LQ + l0 + ll) * DINNER + t;
        float u = x_conv[gi];
        float z = zbuf[gi];
        float dr = bdt2;
        #pragma unroll
        for (int r = 0; r < 12; ++r) dr = fmaf(xd[ll * XDBLP + r], wdt[r], dr);
        float dl = fmaxf(dr, 0.f) + log1pf(__expf(-fabsf(dr)));
        float du = dl * u;
        float yv = 0.f;
        #pragma unroll
        for (int n = 0; n < NST; ++n) {
            h[n] = fmaf(__expf(dl * A[n]), h[n], du * xd[ll * XDBLP + 12 + n]);
            yv = fmaf(h[n], xd[ll * XDBLP + 28 + n], yv);
        }
        yv = fmaf(u, Dd, yv);
        float sig = 1.f / (1.f + __expf(-z));
        ys[ll * DINNER + t] = yv * (z * sig);
    }
    __syncthreads();
    float* dst = yT + ((size_t)(b * DINNER) + t) * LQ + l0;
    #pragma unroll
    for (int q = 0; q < CS; q += 4) {
        float4 v = make_float4(ys[(q+0) * DINNER + t], ys[(q+1) * DINNER + t],
                               ys[(q+2) * DINNER + t], ys[(q+3) * DINNER + t]);
        *(float4*)(dst + q) = v;
    }
}

// ---------------- K8: out[b,c,l] = yT^T @ WoutT (register-tiled, no LDS) ------------
// grid (32 lb, 6 cb, 2 b), block 256 = 4 waves. Thread: 2 l x 8 c.
__global__ __launch_bounds__(256) void k8_out(const float* __restrict__ yT,
                                              const float* __restrict__ WoutT,
                                              float* __restrict__ out) {
    int b = blockIdx.z, cb = blockIdx.y, lb = blockIdx.x;
    int t = threadIdx.x;
    int lane = t & 63;
    int wg = __builtin_amdgcn_readfirstlane(t >> 6);
    int c0 = cb * 32 + wg * 8;
    int l0 = lb * 128;
    const float* yb = yT + (size_t)(b * DINNER) * LQ + l0 + lane;
    float acc0[8], acc1[8];
    #pragma unroll
    for (int i = 0; i < 8; ++i) { acc0[i] = 0.f; acc1[i] = 0.f; }
    #pragma unroll 4
    for (int d = 0; d < DINNER; ++d) {
        float y0 = yb[(size_t)d * LQ];
        float y1 = yb[(size_t)d * LQ + 64];
        const float* Wr = WoutT + (size_t)d * DIMC + c0;   // uniform -> s_load
        #pragma unroll
        for (int i = 0; i < 8; ++i) {
            float w = Wr[i];
            acc0[i] = fmaf(y0, w, acc0[i]);
            acc1[i] = fmaf(y1, w, acc1[i]);
        }
    }
    size_t ob = ((size_t)b * DIMC + c0) * LQ + l0 + lane;
    #pragma unroll
    for (int i = 0; i < 8; ++i) {
        out[ob + (size_t)i * LQ] = acc0[i];
        out[ob + (size_t)i * LQ + 64] = acc1[i];
    }
}

extern "C" void kernel_launch(void* const* d_in, const int* in_sizes, int n_in,
                              void* d_out, int out_size, void* d_ws, size_t ws_size,
                              hipStream_t stream) {
    const float* x      = (const float*)d_in[0];
    const float* W_in   = (const float*)d_in[1];
    const float* conv_w = (const float*)d_in[2];
    const float* conv_b = (const float*)d_in[3];
    const float* W_x    = (const float*)d_in[4];
    const float* W_dt   = (const float*)d_in[5];
    const float* b_dt   = (const float*)d_in[6];
    const float* A_log  = (const float*)d_in[7];
    const float* Dp     = (const float*)d_in[8];
    const float* W_out  = (const float*)d_in[9];
    float* out = (float*)d_out;

    const size_t NBL = (size_t)BQ * LQ * DINNER;     // 3,145,728
    float* w = (float*)d_ws;
    float* x_in    = w; w += NBL;                    // also reused as yT (disjoint lifetime)
    float* zbuf    = w; w += NBL;
    float* x_conv  = w; w += NBL;
    float* x_convT = w; w += NBL;
    float* xdp     = w; w += 4 * (size_t)BQ * LQ * XDBLP;   // 1,572,864
    float* hend    = w; w += (size_t)BQ * NCHUNK * DINNER * NST;
    float* hin     = w; w += (size_t)BQ * NCHUNK * DINNER * NST;
    float* sumd    = w; w += (size_t)BQ * NCHUNK * DINNER;
    float* WxT     = w; w += (size_t)DINNER * XDBLP;
    float* WoutT   = w; w += (size_t)DINNER * DIMC;
    float* yT = x_in;   // x_in dead after k2

    k0_transpose<<<288, 256, 0, stream>>>(W_x, W_out, WxT, WoutT);
    k1_inproj<<<dim3(32, 12, BQ), 256, 0, stream>>>(x, W_in, x_in, zbuf);
    k2_conv<<<dim3(128, BQ), 512, 0, stream>>>(x_in, conv_w, conv_b, x_conv, x_convT);
    k3_xdbl<<<dim3(64, 4, BQ), 256, 0, stream>>>(x_convT, WxT, xdp);
    k5_scanA<<<dim3(NCHUNK, BQ), DINNER, 0, stream>>>(x_conv, xdp, W_dt, b_dt, A_log, hend, sumd);
    k6_combine<<<dim3(DINNER, BQ), 64, 0, stream>>>(A_log, sumd, hend, hin);
    k7_scanC<<<dim3(NCHUNK, BQ), DINNER, 0, stream>>>(x_conv, xdp, W_dt, b_dt, A_log, hin, Dp, zbuf, yT);
    k8_out<<<dim3(32, 6, BQ), 256, 0, stream>>>(yT, WoutT, out);
}

// Round 3
// 256.632 us; speedup vs baseline: 1.2387x; 1.0067x over previous
//
#include <hip/hip_runtime.h>

#define BQ 2
#define DIMC 192
#define DINNER 384
#define LQ 4096
#define NST 16
#define XDBLP 48
#define NCHUNK 256
#define CS 16   // LQ / NCHUNK

// ---------------- K0: transpose weights (W_x -> 384x48 padded, W_out -> 384x192) ----
__global__ void k0_transpose(const float* __restrict__ Wx, const float* __restrict__ Wout,
                             float* __restrict__ WxT, float* __restrict__ WoutT) {
    int t = blockIdx.x * 256 + threadIdx.x;
    if (t < DINNER * XDBLP) {
        int d = t / XDBLP, k = t % XDBLP;
        WxT[t] = (k < 44) ? Wx[k * DINNER + d] : 0.f;
    }
    if (t < DINNER * DIMC) {
        int d = t / DIMC, c = t % DIMC;
        WoutT[t] = Wout[c * DINNER + d];
    }
}

// ---------------- K1: xz = xf @ W_in  (register-tiled, no LDS) ----------------------
// grid (64 lb, 12 mb, 2 b) = 1536 blocks -> 75% occupancy cap. Thread: 1 l x 16 m.
__global__ __launch_bounds__(256) void k1_inproj(const float* __restrict__ x,
                                                 const float* __restrict__ W_in,
                                                 float* __restrict__ x_in,
                                                 float* __restrict__ zbuf) {
    int b = blockIdx.z, lb = blockIdx.x, mb = blockIdx.y;
    int t = threadIdx.x;
    int lane = t & 63;
    int wg = __builtin_amdgcn_readfirstlane(t >> 6);
    int m0 = mb * 64 + wg * 16;
    int l = lb * 64 + lane;
    const float* xb = x + (size_t)b * DIMC * LQ + l;
    float acc[16];
    #pragma unroll
    for (int i = 0; i < 16; ++i) acc[i] = 0.f;
    #pragma unroll 4
    for (int c = 0; c < DIMC; ++c) {
        float xv = xb[(size_t)c * LQ];
        const float* Wr = W_in + (size_t)c * 768 + m0;   // wave-uniform -> s_load
        #pragma unroll
        for (int i = 0; i < 16; ++i) acc[i] = fmaf(xv, Wr[i], acc[i]);
    }
    size_t row = (size_t)(b * LQ + l) * DINNER;
    float* dst = (mb < 6) ? (x_in + row + m0) : (zbuf + row + m0 - DINNER);
    #pragma unroll
    for (int i = 0; i < 16; i += 4)
        *(float4*)(dst + i) = make_float4(acc[i], acc[i+1], acc[i+2], acc[i+3]);
}

// ---------------- K2: causal conv(4)+silu -> x_conv [b,l,d] AND x_convT [b,d,l] -----
// grid (128 lb, 2 b), block 512. 32-l tile, LDS transpose for the T layout.
__global__ __launch_bounds__(512) void k2_conv(const float* __restrict__ x_in,
                                               const float* __restrict__ conv_w,
                                               const float* __restrict__ conv_b,
                                               float* __restrict__ x_conv,
                                               float* __restrict__ x_convT) {
    __shared__ float cs[32 * DINNER];   // 48 KB
    int b = blockIdx.y, lb = blockIdx.x;
    int l0 = lb * 32;
    int t = threadIdx.x;
    #pragma unroll
    for (int it = 0; it < 24; ++it) {
        int e = it * 512 + t;             // 12288 = 32*384
        int ll = e / DINNER, d = e % DINNER;
        int l = l0 + ll;
        size_t gi = (size_t)(b * LQ + l) * DINNER + d;
        float4 w = *(const float4*)(conv_w + d * 4);
        float acc = conv_b[d];
        float v;
        v = (l >= 3) ? x_in[gi - 3 * DINNER] : 0.f; acc = fmaf(w.x, v, acc);
        v = (l >= 2) ? x_in[gi - 2 * DINNER] : 0.f; acc = fmaf(w.y, v, acc);
        v = (l >= 1) ? x_in[gi - 1 * DINNER] : 0.f; acc = fmaf(w.z, v, acc);
        v = x_in[gi];                               acc = fmaf(w.w, v, acc);
        float r = acc / (1.f + __expf(-acc));
        x_conv[gi] = r;
        cs[e] = r;
    }
    __syncthreads();
    if (t < DINNER) {
        float* dst = x_convT + ((size_t)(b * DINNER) + t) * LQ + l0;
        #pragma unroll
        for (int q = 0; q < 32; q += 4) {
            float4 v = make_float4(cs[(q+0) * DINNER + t], cs[(q+1) * DINNER + t],
                                   cs[(q+2) * DINNER + t], cs[(q+3) * DINNER + t]);
            *(float4*)(dst + q) = v;
        }
    }
}

// ---------------- K3: x_dbl partials (split-K=4): p[ds][b,l,48] ---------------------
// grid (64 lb, 4 ds, 2 b), block 256 = 64 l-lanes x 4 kg(12 k each).
__global__ __launch_bounds__(256) void k3_xdbl(const float* __restrict__ x_convT,
                                               const float* __restrict__ WxT,
                                               float* __restrict__ xdp) {
    int b = blockIdx.z, ds = blockIdx.y, lb = blockIdx.x;
    int t = threadIdx.x;
    int lane = t & 63;
    int kg = __builtin_amdgcn_readfirstlane(t >> 6);
    int k0 = kg * 12;
    int l = lb * 64 + lane;
    const float* src = x_convT + (size_t)(b * DINNER + ds * 96) * LQ + l;
    float acc[12];
    #pragma unroll
    for (int i = 0; i < 12; ++i) acc[i] = 0.f;
    #pragma unroll 4
    for (int d = 0; d < 96; ++d) {
        float xv = src[(size_t)d * LQ];
        const float* Wr = WxT + (size_t)(ds * 96 + d) * XDBLP + k0;  // uniform
        #pragma unroll
        for (int i = 0; i < 12; ++i) acc[i] = fmaf(xv, Wr[i], acc[i]);
    }
    float* dst = xdp + (size_t)ds * (BQ * LQ * XDBLP) + (size_t)(b * LQ + l) * XDBLP + k0;
    #pragma unroll
    for (int i = 0; i < 12; i += 4)
        *(float4*)(dst + i) = make_float4(acc[i], acc[i+1], acc[i+2], acc[i+3]);
}

// ---------------- K5: scan pass A — local chunk scan, inline delta ------------------
// grid (256 ch, 2 b), block 384 (thread = d). hend[b][ch][d][n], sumd[b][ch][d].
__global__ __launch_bounds__(DINNER) void k5_scanA(const float* __restrict__ x_conv,
                                                   const float* __restrict__ xdp,
                                                   const float* __restrict__ W_dt,
                                                   const float* __restrict__ b_dt,
                                                   const float* __restrict__ A_log,
                                                   float* __restrict__ hend,
                                                   float* __restrict__ sumd) {
    __shared__ float xd[CS * XDBLP];   // 3 KB: dt|B|C rows for this chunk
    int b = blockIdx.y, ch = blockIdx.x;
    int l0 = ch * CS;
    int t = threadIdx.x;
    const size_t PD = (size_t)BQ * LQ * XDBLP;
    size_t base = (size_t)(b * LQ + l0) * XDBLP;
    for (int idx = t; idx < CS * XDBLP; idx += DINNER)
        xd[idx] = xdp[base + idx] + xdp[PD + base + idx]
                + xdp[2 * PD + base + idx] + xdp[3 * PD + base + idx];
    float wdt[12];
    #pragma unroll
    for (int r = 0; r < 12; r += 4) {
        float4 v = *(const float4*)(W_dt + t * 12 + r);
        wdt[r] = v.x; wdt[r+1] = v.y; wdt[r+2] = v.z; wdt[r+3] = v.w;
    }
    float bdt2 = 2.f * b_dt[t];
    float A[NST];
    #pragma unroll
    for (int n = 0; n < NST; ++n) A[n] = -__expf(A_log[t * NST + n]);
    __syncthreads();
    float h[NST];
    #pragma unroll
    for (int n = 0; n < NST; ++n) h[n] = 0.f;
    float sd = 0.f;
    for (int ll = 0; ll < CS; ++ll) {
        float u = x_conv[(size_t)(b * LQ + l0 + ll) * DINNER + t];
        float dr = bdt2;
        #pragma unroll
        for (int r = 0; r < 12; ++r) dr = fmaf(xd[ll * XDBLP + r], wdt[r], dr);
        float dl = fmaxf(dr, 0.f) + log1pf(__expf(-fabsf(dr)));   // softplus
        sd += dl;
        float du = dl * u;
        #pragma unroll
        for (int n = 0; n < NST; ++n)
            h[n] = fmaf(__expf(dl * A[n]), h[n], du * xd[ll * XDBLP + 12 + n]);
    }
    // [b][ch][d][n]: each thread writes 64B contiguous; wave writes 4 KB contiguous
    size_t hb = ((size_t)(b * NCHUNK + ch) * DINNER + t) * NST;
    #pragma unroll
    for (int n = 0; n < NST; n += 4)
        *(float4*)(hend + hb + n) = make_float4(h[n], h[n+1], h[n+2], h[n+3]);
    sumd[(size_t)(b * NCHUNK + ch) * DINNER + t] = sd;
}

// ---------------- K6: chunk-carry combine, parallel per (b,d) -----------------------
// grid (384 d, 2 b), block 64 = 16 n x 4 chunk-groups of 64.
__global__ __launch_bounds__(64) void k6_combine(const float* __restrict__ A_log,
                                                 const float* __restrict__ sumd,
                                                 const float* __restrict__ hend,
                                                 float* __restrict__ hin) {
    __shared__ float As[4][NST], Bs[4][NST];
    int d = blockIdx.x, b = blockIdx.y;
    int t = threadIdx.x;
    int n = t & 15, g = t >> 4;
    float A = -__expf(A_log[d * NST + n]);
    float ca = 1.f, cb = 0.f;
    #pragma unroll 4
    for (int i = 0; i < 64; ++i) {
        int ch = g * 64 + i;
        float a = __expf(A * sumd[(size_t)(b * NCHUNK + ch) * DINNER + d]);
        float bh = hend[((size_t)(b * NCHUNK + ch) * DINNER + d) * NST + n];
        ca *= a;
        cb = fmaf(a, cb, bh);
    }
    As[g][n] = ca; Bs[g][n] = cb;
    __syncthreads();
    float carry = 0.f;                       // h0 = 0
    for (int j = 0; j < g; ++j) carry = fmaf(As[j][n], carry, Bs[j][n]);
    #pragma unroll 4
    for (int i = 0; i < 64; ++i) {
        int ch = g * 64 + i;
        size_t idx = ((size_t)(b * NCHUNK + ch) * DINNER + d) * NST + n;
        hin[idx] = carry;
        float a = __expf(A * sumd[(size_t)(b * NCHUNK + ch) * DINNER + d]);
        carry = fmaf(a, carry, hend[idx]);
    }
}

// ---------------- K7: scan pass C — inline delta, gate, emit yT[b,d,l] --------------
// grid (256 ch, 2 b), block 384.
__global__ __launch_bounds__(DINNER) void k7_scanC(const float* __restrict__ x_conv,
                                                   const float* __restrict__ xdp,
                                                   const float* __restrict__ W_dt,
                                                   const float* __restrict__ b_dt,
                                                   const float* __restrict__ A_log,
                                                   const float* __restrict__ hin,
                                                   const float* __restrict__ Dp,
                                                   const float* __restrict__ zbuf,
                                                   float* __restrict__ yT) {
    __shared__ float xd[CS * XDBLP];       // 3 KB
    __shared__ float ys[CS * DINNER];      // 24.6 KB
    int b = blockIdx.y, ch = blockIdx.x;
    int l0 = ch * CS;
    int t = threadIdx.x;
    const size_t PD = (size_t)BQ * LQ * XDBLP;
    size_t base = (size_t)(b * LQ + l0) * XDBLP;
    for (int idx = t; idx < CS * XDBLP; idx += DINNER)
        xd[idx] = xdp[base + idx] + xdp[PD + base + idx]
                + xdp[2 * PD + base + idx] + xdp[3 * PD + base + idx];
    float wdt[12];
    #pragma unroll
    for (int r = 0; r < 12; r += 4) {
        float4 v = *(const float4*)(W_dt + t * 12 + r);
        wdt[r] = v.x; wdt[r+1] = v.y; wdt[r+2] = v.z; wdt[r+3] = v.w;
    }
    float bdt2 = 2.f * b_dt[t];
    float A[NST];
    #pragma unroll
    for (int n = 0; n < NST; ++n) A[n] = -__expf(A_log[t * NST + n]);
    float h[NST];
    size_t hb = ((size_t)(b * NCHUNK + ch) * DINNER + t) * NST;
    #pragma unroll
    for (int n = 0; n < NST; n += 4) {
        float4 v = *(const float4*)(hin + hb + n);
        h[n] = v.x; h[n+1] = v.y; h[n+2] = v.z; h[n+3] = v.w;
    }
    float Dd = Dp[t];
    __syncthreads();
    for (int ll = 0; ll < CS; ++ll) {
        size_t gi = (size_t)(b * LQ + l0 + ll) * DINNER + t;
        float u = x_conv[gi];
        float z = zbuf[gi];
        float dr = bdt2;
        #pragma unroll
        for (int r = 0; r < 12; ++r) dr = fmaf(xd[ll * XDBLP + r], wdt[r], dr);
        float dl = fmaxf(dr, 0.f) + log1pf(__expf(-fabsf(dr)));
        float du = dl * u;
        float yv = 0.f;
        #pragma unroll
        for (int n = 0; n < NST; ++n) {
            h[n] = fmaf(__expf(dl * A[n]), h[n], du * xd[ll * XDBLP + 12 + n]);
            yv = fmaf(h[n], xd[ll * XDBLP + 28 + n], yv);
        }
        yv = fmaf(u, Dd, yv);
        float sig = 1.f / (1.f + __expf(-z));
        ys[ll * DINNER + t] = yv * (z * sig);
    }
    __syncthreads();
    float* dst = yT + ((size_t)(b * DINNER) + t) * LQ + l0;
    #pragma unroll
    for (int q = 0; q < CS; q += 4) {
        float4 v = make_float4(ys[(q+0) * DINNER + t], ys[(q+1) * DINNER + t],
                               ys[(q+2) * DINNER + t], ys[(q+3) * DINNER + t]);
        *(float4*)(dst + q) = v;
    }
}

// ---------------- K8: out[b,c,l] = yT^T @ WoutT (register-tiled, no LDS) ------------
// grid (64 lb, 6 cb, 2 b) = 768 blocks. Thread: 1 l x 8 c.
__global__ __launch_bounds__(256) void k8_out(const float* __restrict__ yT,
                                              const float* __restrict__ WoutT,
                                              float* __restrict__ out) {
    int b = blockIdx.z, cb = blockIdx.y, lb = blockIdx.x;
    int t = threadIdx.x;
    int lane = t & 63;
    int wg = __builtin_amdgcn_readfirstlane(t >> 6);
    int c0 = cb * 32 + wg * 8;
    int l = lb * 64 + lane;
    const float* yb = yT + (size_t)(b * DINNER) * LQ + l;
    float acc[8];
    #pragma unroll
    for (int i = 0; i < 8; ++i) acc[i] = 0.f;
    #pragma unroll 8
    for (int d = 0; d < DINNER; ++d) {
        float y0 = yb[(size_t)d * LQ];
        const float* Wr = WoutT + (size_t)d * DIMC + c0;   // uniform -> s_load
        #pragma unroll
        for (int i = 0; i < 8; ++i) acc[i] = fmaf(y0, Wr[i], acc[i]);
    }
    size_t ob = ((size_t)b * DIMC + c0) * LQ + l;
    #pragma unroll
    for (int i = 0; i < 8; ++i) out[ob + (size_t)i * LQ] = acc[i];
}

extern "C" void kernel_launch(void* const* d_in, const int* in_sizes, int n_in,
                              void* d_out, int out_size, void* d_ws, size_t ws_size,
                              hipStream_t stream) {
    const float* x      = (const float*)d_in[0];
    const float* W_in   = (const float*)d_in[1];
    const float* conv_w = (const float*)d_in[2];
    const float* conv_b = (const float*)d_in[3];
    const float* W_x    = (const float*)d_in[4];
    const float* W_dt   = (const float*)d_in[5];
    const float* b_dt   = (const float*)d_in[6];
    const float* A_log  = (const float*)d_in[7];
    const float* Dp     = (const float*)d_in[8];
    const float* W_out  = (const float*)d_in[9];
    float* out = (float*)d_out;

    const size_t NBL = (size_t)BQ * LQ * DINNER;     // 3,145,728
    float* w = (float*)d_ws;
    float* x_in    = w; w += NBL;                    // also reused as yT (disjoint lifetime)
    float* zbuf    = w; w += NBL;
    float* x_conv  = w; w += NBL;
    float* x_convT = w; w += NBL;
    float* xdp     = w; w += 4 * (size_t)BQ * LQ * XDBLP;   // 1,572,864
    float* hend    = w; w += (size_t)BQ * NCHUNK * DINNER * NST;
    float* hin     = w; w += (size_t)BQ * NCHUNK * DINNER * NST;
    float* sumd    = w; w += (size_t)BQ * NCHUNK * DINNER;
    float* WxT     = w; w += (size_t)DINNER * XDBLP;
    float* WoutT   = w; w += (size_t)DINNER * DIMC;
    float* yT = x_in;   // x_in dead after k2

    k0_transpose<<<288, 256, 0, stream>>>(W_x, W_out, WxT, WoutT);
    k1_inproj<<<dim3(64, 12, BQ), 256, 0, stream>>>(x, W_in, x_in, zbuf);
    k2_conv<<<dim3(128, BQ), 512, 0, stream>>>(x_in, conv_w, conv_b, x_conv, x_convT);
    k3_xdbl<<<dim3(64, 4, BQ), 256, 0, stream>>>(x_convT, WxT, xdp);
    k5_scanA<<<dim3(NCHUNK, BQ), DINNER, 0, stream>>>(x_conv, xdp, W_dt, b_dt, A_log, hend, sumd);
    k6_combine<<<dim3(DINNER, BQ), 64, 0, stream>>>(A_log, sumd, hend, hin);
    k7_scanC<<<dim3(NCHUNK, BQ), DINNER, 0, stream>>>(x_conv, xdp, W_dt, b_dt, A_log, hin, Dp, zbuf, yT);
    k8_out<<<dim3(64, 6, BQ), 256, 0, stream>>>(yT, WoutT, out);
}

// Round 4
// 237.315 us; speedup vs baseline: 1.3395x; 1.0814x over previous
//
#include <hip/hip_runtime.h>

#define BQ 2
#define DIMC 192
#define DINNER 384
#define LQ 4096
#define NST 16
#define XDBLP 48
#define NCHUNK 256
#define CS 16   // LQ / NCHUNK

// ---------------- K0: transpose weights (W_x -> 384x48 padded, W_out -> 384x192) ----
__global__ void k0_transpose(const float* __restrict__ Wx, const float* __restrict__ Wout,
                             float* __restrict__ WxT, float* __restrict__ WoutT) {
    int t = blockIdx.x * 256 + threadIdx.x;
    if (t < DINNER * XDBLP) {
        int d = t / XDBLP, k = t % XDBLP;
        WxT[t] = (k < 44) ? Wx[k * DINNER + d] : 0.f;
    }
    if (t < DINNER * DIMC) {
        int d = t / DIMC, c = t % DIMC;
        WoutT[t] = Wout[c * DINNER + d];
    }
}

// ---------------- K1: xz partials, split-K over c --------------------------------
// grid (64 lb, 24 = 12 mb x 2 ks, 2 b) = 3072 blocks. Thread: 1 l x 16 m, 96 c.
__global__ __launch_bounds__(256) void k1_inproj(const float* __restrict__ x,
                                                 const float* __restrict__ W_in,
                                                 float* __restrict__ xzp0,
                                                 float* __restrict__ xzp1) {
    int b = blockIdx.z, lb = blockIdx.x;
    int mb = blockIdx.y >> 1, ks = blockIdx.y & 1;
    int t = threadIdx.x;
    int lane = t & 63;
    int wg = __builtin_amdgcn_readfirstlane(t >> 6);
    int m0 = mb * 64 + wg * 16;
    int l = lb * 64 + lane;
    const float* xb = x + (size_t)b * DIMC * LQ + (size_t)ks * 96 * LQ + l;
    float acc[16];
    #pragma unroll
    for (int i = 0; i < 16; ++i) acc[i] = 0.f;
    #pragma unroll 4
    for (int c = 0; c < 96; ++c) {
        float xv = xb[(size_t)c * LQ];
        const float* Wr = W_in + (size_t)(ks * 96 + c) * 768 + m0;   // uniform -> s_load
        #pragma unroll
        for (int i = 0; i < 16; ++i) acc[i] = fmaf(xv, Wr[i], acc[i]);
    }
    float* dst = (ks ? xzp1 : xzp0) + (size_t)(b * LQ + l) * 768 + m0;
    #pragma unroll
    for (int i = 0; i < 16; i += 4)
        *(float4*)(dst + i) = make_float4(acc[i], acc[i+1], acc[i+2], acc[i+3]);
}

// ---------------- K2: fold partials + causal conv(4)+silu -> x_conv, x_convT --------
// grid (256 lb, 2 b), block 384 (thread = d). Sliding window over 16-l tile.
__global__ __launch_bounds__(384) void k2_conv(const float* __restrict__ xzp0,
                                               const float* __restrict__ xzp1,
                                               const float* __restrict__ conv_w,
                                               const float* __restrict__ conv_b,
                                               float* __restrict__ x_conv,
                                               float* __restrict__ x_convT) {
    __shared__ float cs[16 * DINNER];   // 24.6 KB
    int b = blockIdx.y, lb = blockIdx.x;
    int l0 = lb * 16;
    int t = threadIdx.x;   // = d
    float4 w = *(const float4*)(conv_w + t * 4);
    float bias = conv_b[t];
    float xm3 = 0.f, xm2 = 0.f, xm1 = 0.f;
    #pragma unroll
    for (int i = 3; i >= 1; --i) {
        int l = l0 - i;
        float v = 0.f;
        if (l >= 0) {
            size_t r = (size_t)(b * LQ + l) * 768 + t;
            v = xzp0[r] + xzp1[r];
        }
        xm3 = xm2; xm2 = xm1; xm1 = v;
    }
    #pragma unroll
    for (int ll = 0; ll < 16; ++ll) {
        int l = l0 + ll;
        size_t r = (size_t)(b * LQ + l) * 768 + t;
        float v = xzp0[r] + xzp1[r];
        float acc = bias;
        acc = fmaf(w.x, xm3, acc);
        acc = fmaf(w.y, xm2, acc);
        acc = fmaf(w.z, xm1, acc);
        acc = fmaf(w.w, v, acc);
        float rr = acc / (1.f + __expf(-acc));
        x_conv[(size_t)(b * LQ + l) * DINNER + t] = rr;
        cs[ll * DINNER + t] = rr;
        xm3 = xm2; xm2 = xm1; xm1 = v;
    }
    __syncthreads();
    float* dst = x_convT + ((size_t)(b * DINNER) + t) * LQ + l0;
    #pragma unroll
    for (int q = 0; q < 16; q += 4) {
        float4 v = make_float4(cs[(q+0) * DINNER + t], cs[(q+1) * DINNER + t],
                               cs[(q+2) * DINNER + t], cs[(q+3) * DINNER + t]);
        *(float4*)(dst + q) = v;
    }
}

// ---------------- K3: x_dbl partials (split-K=4): p[ds][b,l,48] ---------------------
__global__ __launch_bounds__(256) void k3_xdbl(const float* __restrict__ x_convT,
                                               const float* __restrict__ WxT,
                                               float* __restrict__ xdp) {
    int b = blockIdx.z, ds = blockIdx.y, lb = blockIdx.x;
    int t = threadIdx.x;
    int lane = t & 63;
    int kg = __builtin_amdgcn_readfirstlane(t >> 6);
    int k0 = kg * 12;
    int l = lb * 64 + lane;
    const float* src = x_convT + (size_t)(b * DINNER + ds * 96) * LQ + l;
    float acc[12];
    #pragma unroll
    for (int i = 0; i < 12; ++i) acc[i] = 0.f;
    #pragma unroll 4
    for (int d = 0; d < 96; ++d) {
        float xv = src[(size_t)d * LQ];
        const float* Wr = WxT + (size_t)(ds * 96 + d) * XDBLP + k0;  // uniform
        #pragma unroll
        for (int i = 0; i < 12; ++i) acc[i] = fmaf(xv, Wr[i], acc[i]);
    }
    float* dst = xdp + (size_t)ds * (BQ * LQ * XDBLP) + (size_t)(b * LQ + l) * XDBLP + k0;
    #pragma unroll
    for (int i = 0; i < 12; i += 4)
        *(float4*)(dst + i) = make_float4(acc[i], acc[i+1], acc[i+2], acc[i+3]);
}

// ---------------- K5: scan pass A — local scan; emit hend, sumd, y_part, sdc --------
// grid (256 ch, 2 b), block 384 (thread = d).
__global__ __launch_bounds__(DINNER) void k5_scanA(const float* __restrict__ x_conv,
                                                   const float* __restrict__ xdp,
                                                   const float* __restrict__ W_dt,
                                                   const float* __restrict__ b_dt,
                                                   const float* __restrict__ A_log,
                                                   float* __restrict__ hend,
                                                   float* __restrict__ sumd,
                                                   float* __restrict__ ypart,
                                                   float* __restrict__ sdc) {
    __shared__ float xd[CS * XDBLP];   // 3 KB: dt|B|C rows for this chunk
    int b = blockIdx.y, ch = blockIdx.x;
    int l0 = ch * CS;
    int t = threadIdx.x;
    const size_t PD = (size_t)BQ * LQ * XDBLP;
    size_t base = (size_t)(b * LQ + l0) * XDBLP;
    for (int idx = t; idx < CS * XDBLP; idx += DINNER)
        xd[idx] = xdp[base + idx] + xdp[PD + base + idx]
                + xdp[2 * PD + base + idx] + xdp[3 * PD + base + idx];
    float wdt[12];
    #pragma unroll
    for (int r = 0; r < 12; r += 4) {
        float4 v = *(const float4*)(W_dt + t * 12 + r);
        wdt[r] = v.x; wdt[r+1] = v.y; wdt[r+2] = v.z; wdt[r+3] = v.w;
    }
    float bdt2 = 2.f * b_dt[t];
    float A[NST];
    #pragma unroll
    for (int n = 0; n < NST; ++n) A[n] = -__expf(A_log[t * NST + n]);
    __syncthreads();
    float h[NST];
    #pragma unroll
    for (int n = 0; n < NST; ++n) h[n] = 0.f;
    float sd = 0.f;
    for (int ll = 0; ll < CS; ++ll) {
        size_t gi = (size_t)(b * LQ + l0 + ll) * DINNER + t;
        float u = x_conv[gi];
        // 3-way split dep chain for delta
        float d0 = bdt2, d1 = 0.f, d2 = 0.f;
        #pragma unroll
        for (int r = 0; r < 4; ++r) {
            d0 = fmaf(xd[ll * XDBLP + r], wdt[r], d0);
            d1 = fmaf(xd[ll * XDBLP + 4 + r], wdt[4 + r], d1);
            d2 = fmaf(xd[ll * XDBLP + 8 + r], wdt[8 + r], d2);
        }
        float dr = d0 + d1 + d2;
        float dl = fmaxf(dr, 0.f) + log1pf(__expf(-fabsf(dr)));   // softplus
        sd += dl;
        sdc[gi] = sd;
        float du = dl * u;
        float yv = 0.f;
        #pragma unroll
        for (int n = 0; n < NST; ++n) {
            h[n] = fmaf(__expf(dl * A[n]), h[n], du * xd[ll * XDBLP + 12 + n]);
            yv = fmaf(h[n], xd[ll * XDBLP + 28 + n], yv);
        }
        ypart[gi] = yv;
    }
    size_t hb = ((size_t)(b * NCHUNK + ch) * DINNER + t) * NST;
    #pragma unroll
    for (int n = 0; n < NST; n += 4)
        *(float4*)(hend + hb + n) = make_float4(h[n], h[n+1], h[n+2], h[n+3]);
    sumd[(size_t)(b * NCHUNK + ch) * DINNER + t] = sd;
}

// ---------------- K6: chunk-carry combine, 16 segments x 16 chunks ------------------
// grid (384 d, 2 b), block 256 = 16 n x 16 segments.
__global__ __launch_bounds__(256) void k6_combine(const float* __restrict__ A_log,
                                                  const float* __restrict__ sumd,
                                                  const float* __restrict__ hend,
                                                  float* __restrict__ hin) {
    __shared__ float As[16][NST], Bs[16][NST];
    int d = blockIdx.x, b = blockIdx.y;
    int t = threadIdx.x;
    int n = t & 15, g = t >> 4;
    float A = -__expf(A_log[d * NST + n]);
    float ca = 1.f, cb = 0.f;
    #pragma unroll
    for (int i = 0; i < 16; ++i) {
        int ch = g * 16 + i;
        float a = __expf(A * sumd[(size_t)(b * NCHUNK + ch) * DINNER + d]);
        float bh = hend[((size_t)(b * NCHUNK + ch) * DINNER + d) * NST + n];
        ca *= a;
        cb = fmaf(a, cb, bh);
    }
    As[g][n] = ca; Bs[g][n] = cb;
    __syncthreads();
    float carry = 0.f;                       // h0 = 0
    for (int j = 0; j < g; ++j) carry = fmaf(As[j][n], carry, Bs[j][n]);
    #pragma unroll
    for (int i = 0; i < 16; ++i) {
        int ch = g * 16 + i;
        size_t idx = ((size_t)(b * NCHUNK + ch) * DINNER + d) * NST + n;
        hin[idx] = carry;
        float a = __expf(A * sumd[(size_t)(b * NCHUNK + ch) * DINNER + d]);
        carry = fmaf(a, carry, hend[idx]);
    }
}

// ---------------- K7: pass C — PARALLEL correction + gate, emit yT[b,d,l] -----------
// y = ypart + sum_n exp(A[n]*sdc)*carry[n]*C[l,n]; then +u*D, *silu(z).
// grid (256 ch, 2 b), block 384.
__global__ __launch_bounds__(DINNER) void k7_passC(const float* __restrict__ x_conv,
                                                   const float* __restrict__ xdp,
                                                   const float* __restrict__ A_log,
                                                   const float* __restrict__ hin,
                                                   const float* __restrict__ Dp,
                                                   const float* __restrict__ xzp0,
                                                   const float* __restrict__ xzp1,
                                                   const float* __restrict__ ypart,
                                                   const float* __restrict__ sdc,
                                                   float* __restrict__ yT) {
    __shared__ float cxd[CS * NST];        // C rows, 1 KB
    __shared__ float ys[CS * DINNER];      // 24.6 KB
    int b = blockIdx.y, ch = blockIdx.x;
    int l0 = ch * CS;
    int t = threadIdx.x;
    const size_t PD = (size_t)BQ * LQ * XDBLP;
    for (int idx = t; idx < CS * NST; idx += DINNER) {
        int ll = idx >> 4, n = idx & 15;
        size_t r = (size_t)(b * LQ + l0 + ll) * XDBLP + 28 + n;
        cxd[idx] = xdp[r] + xdp[PD + r] + xdp[2 * PD + r] + xdp[3 * PD + r];
    }
    float A[NST];
    #pragma unroll
    for (int n = 0; n < NST; ++n) A[n] = -__expf(A_log[t * NST + n]);
    float carry[NST];
    size_t hb = ((size_t)(b * NCHUNK + ch) * DINNER + t) * NST;
    #pragma unroll
    for (int n = 0; n < NST; n += 4) {
        float4 v = *(const float4*)(hin + hb + n);
        carry[n] = v.x; carry[n+1] = v.y; carry[n+2] = v.z; carry[n+3] = v.w;
    }
    float Dd = Dp[t];
    __syncthreads();
    #pragma unroll 4
    for (int ll = 0; ll < CS; ++ll) {
        size_t gi = (size_t)(b * LQ + l0 + ll) * DINNER + t;
        size_t zr = (size_t)(b * LQ + l0 + ll) * 768 + 384 + t;
        float yv = ypart[gi];
        float sc = sdc[gi];
        float u  = x_conv[gi];
        float z  = xzp0[zr] + xzp1[zr];
        #pragma unroll
        for (int n = 0; n < NST; ++n)
            yv = fmaf(__expf(A[n] * sc) * carry[n], cxd[ll * NST + n], yv);
        yv = fmaf(u, Dd, yv);
        float sig = 1.f / (1.f + __expf(-z));
        ys[ll * DINNER + t] = yv * (z * sig);
    }
    __syncthreads();
    float* dst = yT + ((size_t)(b * DINNER) + t) * LQ + l0;
    #pragma unroll
    for (int q = 0; q < CS; q += 4) {
        float4 v = make_float4(ys[(q+0) * DINNER + t], ys[(q+1) * DINNER + t],
                               ys[(q+2) * DINNER + t], ys[(q+3) * DINNER + t]);
        *(float4*)(dst + q) = v;
    }
}

// ---------------- K8: out partials, split-K over d ----------------------------------
// grid (64 lb, 6 cb, 4 = 2 b x 2 ds). Thread: 1 l x 8 c, 192 d.
__global__ __launch_bounds__(256) void k8_out(const float* __restrict__ yT,
                                              const float* __restrict__ WoutT,
                                              float* __restrict__ op0,
                                              float* __restrict__ op1) {
    int b = blockIdx.z >> 1, ds = blockIdx.z & 1;
    int cb = blockIdx.y, lb = blockIdx.x;
    int t = threadIdx.x;
    int lane = t & 63;
    int wg = __builtin_amdgcn_readfirstlane(t >> 6);
    int c0 = cb * 32 + wg * 8;
    int l = lb * 64 + lane;
    const float* yb = yT + (size_t)(b * DINNER + ds * 192) * LQ + l;
    float acc[8];
    #pragma unroll
    for (int i = 0; i < 8; ++i) acc[i] = 0.f;
    #pragma unroll 8
    for (int d = 0; d < 192; ++d) {
        float y0 = yb[(size_t)d * LQ];
        const float* Wr = WoutT + (size_t)(ds * 192 + d) * DIMC + c0;   // uniform
        #pragma unroll
        for (int i = 0; i < 8; ++i) acc[i] = fmaf(y0, Wr[i], acc[i]);
    }
    float* op = ds ? op1 : op0;
    size_t ob = ((size_t)b * DIMC + c0) * LQ + l;
    #pragma unroll
    for (int i = 0; i < 8; ++i) op[ob + (size_t)i * LQ] = acc[i];
}

// ---------------- K9: out = op0 + op1 ----------------------------------------------
__global__ __launch_bounds__(256) void k9_sum(const float* __restrict__ op0,
                                              const float* __restrict__ op1,
                                              float* __restrict__ out) {
    size_t i = ((size_t)blockIdx.x * 256 + threadIdx.x) * 4;
    float4 a = *(const float4*)(op0 + i);
    float4 c = *(const float4*)(op1 + i);
    *(float4*)(out + i) = make_float4(a.x + c.x, a.y + c.y, a.z + c.z, a.w + c.w);
}

extern "C" void kernel_launch(void* const* d_in, const int* in_sizes, int n_in,
                              void* d_out, int out_size, void* d_ws, size_t ws_size,
                              hipStream_t stream) {
    const float* x      = (const float*)d_in[0];
    const float* W_in   = (const float*)d_in[1];
    const float* conv_w = (const float*)d_in[2];
    const float* conv_b = (const float*)d_in[3];
    const float* W_x    = (const float*)d_in[4];
    const float* W_dt   = (const float*)d_in[5];
    const float* b_dt   = (const float*)d_in[6];
    const float* A_log  = (const float*)d_in[7];
    const float* Dp     = (const float*)d_in[8];
    const float* W_out  = (const float*)d_in[9];
    float* out = (float*)d_out;

    const size_t NBL = (size_t)BQ * LQ * DINNER;     // 3,145,728
    float* w = (float*)d_ws;
    float* xzp0    = w; w += (size_t)BQ * LQ * 768;  // 6,291,456
    float* xzp1    = w; w += (size_t)BQ * LQ * 768;
    float* x_conv  = w; w += NBL;
    float* x_convT = w; w += NBL;
    float* xdp     = w; w += 4 * (size_t)BQ * LQ * XDBLP;
    float* hend    = w; w += (size_t)BQ * NCHUNK * DINNER * NST;
    float* hin     = w; w += (size_t)BQ * NCHUNK * DINNER * NST;
    float* sumd    = w; w += (size_t)BQ * NCHUNK * DINNER;
    float* ypart   = w; w += NBL;
    float* sdcb    = w; w += NBL;
    float* op0     = w; w += (size_t)BQ * DIMC * LQ;
    float* op1     = w; w += (size_t)BQ * DIMC * LQ;
    float* WxT     = w; w += (size_t)DINNER * XDBLP;
    float* WoutT   = w; w += (size_t)DINNER * DIMC;
    float* yT = x_convT;   // x_convT dead after k3

    k0_transpose<<<288, 256, 0, stream>>>(W_x, W_out, WxT, WoutT);
    k1_inproj<<<dim3(64, 24, BQ), 256, 0, stream>>>(x, W_in, xzp0, xzp1);
    k2_conv<<<dim3(256, BQ), 384, 0, stream>>>(xzp0, xzp1, conv_w, conv_b, x_conv, x_convT);
    k3_xdbl<<<dim3(64, 4, BQ), 256, 0, stream>>>(x_convT, WxT, xdp);
    k5_scanA<<<dim3(NCHUNK, BQ), DINNER, 0, stream>>>(x_conv, xdp, W_dt, b_dt, A_log,
                                                      hend, sumd, ypart, sdcb);
    k6_combine<<<dim3(DINNER, BQ), 256, 0, stream>>>(A_log, sumd, hend, hin);
    k7_passC<<<dim3(NCHUNK, BQ), DINNER, 0, stream>>>(x_conv, xdp, A_log, hin, Dp,
                                                      xzp0, xzp1, ypart, sdcb, yT);
    k8_out<<<dim3(64, 6, 2 * BQ), 256, 0, stream>>>(yT, WoutT, op0, op1);
    k9_sum<<<(BQ * DIMC * LQ) / 1024, 256, 0, stream>>>(op0, op1, out);
}

// Round 5
// 229.270 us; speedup vs baseline: 1.3865x; 1.0351x over previous
//
#include <hip/hip_runtime.h>

#define BQ 2
#define DIMC 192
#define DINNER 384
#define LQ 4096
#define NST 16
#define XDBLP 48
#define NCHUNK 256
#define CS 16   // LQ / NCHUNK

// ---------------- K0: transpose weights (W_x -> 384x48 padded, W_out -> 384x192) ----
__global__ void k0_transpose(const float* __restrict__ Wx, const float* __restrict__ Wout,
                             float* __restrict__ WxT, float* __restrict__ WoutT) {
    int t = blockIdx.x * 256 + threadIdx.x;
    if (t < DINNER * XDBLP) {
        int d = t / XDBLP, k = t % XDBLP;
        WxT[t] = (k < 44) ? Wx[k * DINNER + d] : 0.f;
    }
    if (t < DINNER * DIMC) {
        int d = t / DIMC, c = t % DIMC;
        WoutT[t] = Wout[c * DINNER + d];
    }
}

// ---------------- K1: xz = xf @ W_in — lanes=m, weights on vector pipe --------------
// grid (256 lb, 3 mb, 2 b), block 256 = 4 waves. Wave: 64 lanes x 4 m-regs = 256 m,
// own l-quad. x-tile (192c x 16l = 12 KB) in LDS, read as wave-uniform b128.
__global__ __launch_bounds__(256) void k1_inproj(const float* __restrict__ x,
                                                 const float* __restrict__ W_in,
                                                 float* __restrict__ xz) {
    __shared__ float xs[DIMC * 16];   // 12 KB, [c][ll]
    int b = blockIdx.z, lb = blockIdx.x, mb = blockIdx.y;
    int t = threadIdx.x;
    int l0 = lb * 16;
    const float* xb = x + (size_t)b * DIMC * LQ + l0;
    #pragma unroll
    for (int it = 0; it < 12; ++it) {
        int e = it * 256 + t;                // 3072 = 192*16
        int c = e >> 4, ll = e & 15;
        xs[e] = xb[(size_t)c * LQ + ll];     // 64B segments, once per block
    }
    __syncthreads();
    int lane = t & 63;
    int wq = __builtin_amdgcn_readfirstlane(t >> 6);   // wave's l-quad
    int m0 = mb * 256 + lane;
    float acc[4][4];
    #pragma unroll
    for (int k = 0; k < 4; ++k)
        #pragma unroll
        for (int j = 0; j < 4; ++j) acc[k][j] = 0.f;
    const float* Wb = W_in + m0;
    #pragma unroll 4
    for (int c = 0; c < DIMC; ++c) {
        float4 xq = *(const float4*)(xs + c * 16 + wq * 4);   // uniform broadcast
        float w0 = Wb[(size_t)c * 768];
        float w1 = Wb[(size_t)c * 768 + 64];
        float w2 = Wb[(size_t)c * 768 + 128];
        float w3 = Wb[(size_t)c * 768 + 192];
        acc[0][0] = fmaf(w0, xq.x, acc[0][0]); acc[0][1] = fmaf(w0, xq.y, acc[0][1]);
        acc[0][2] = fmaf(w0, xq.z, acc[0][2]); acc[0][3] = fmaf(w0, xq.w, acc[0][3]);
        acc[1][0] = fmaf(w1, xq.x, acc[1][0]); acc[1][1] = fmaf(w1, xq.y, acc[1][1]);
        acc[1][2] = fmaf(w1, xq.z, acc[1][2]); acc[1][3] = fmaf(w1, xq.w, acc[1][3]);
        acc[2][0] = fmaf(w2, xq.x, acc[2][0]); acc[2][1] = fmaf(w2, xq.y, acc[2][1]);
        acc[2][2] = fmaf(w2, xq.z, acc[2][2]); acc[2][3] = fmaf(w2, xq.w, acc[2][3]);
        acc[3][0] = fmaf(w3, xq.x, acc[3][0]); acc[3][1] = fmaf(w3, xq.y, acc[3][1]);
        acc[3][2] = fmaf(w3, xq.z, acc[3][2]); acc[3][3] = fmaf(w3, xq.w, acc[3][3]);
    }
    #pragma unroll
    for (int j = 0; j < 4; ++j) {
        float* dst = xz + (size_t)(b * LQ + l0 + wq * 4 + j) * 768 + m0;
        dst[0]   = acc[0][j];
        dst[64]  = acc[1][j];
        dst[128] = acc[2][j];
        dst[192] = acc[3][j];
    }
}

// ---------------- K2: causal conv(4)+silu -> x_conv [b,l,d] AND x_convT [b,d,l] -----
// grid (256 lb, 2 b), block 384 (thread = d). Sliding window over 16-l tile.
__global__ __launch_bounds__(384) void k2_conv(const float* __restrict__ xz,
                                               const float* __restrict__ conv_w,
                                               const float* __restrict__ conv_b,
                                               float* __restrict__ x_conv,
                                               float* __restrict__ x_convT) {
    __shared__ float cs[16 * DINNER];   // 24.6 KB
    int b = blockIdx.y, lb = blockIdx.x;
    int l0 = lb * 16;
    int t = threadIdx.x;   // = d
    float4 w = *(const float4*)(conv_w + t * 4);
    float bias = conv_b[t];
    float xm3 = 0.f, xm2 = 0.f, xm1 = 0.f;
    #pragma unroll
    for (int i = 3; i >= 1; --i) {
        int l = l0 - i;
        float v = (l >= 0) ? xz[(size_t)(b * LQ + l) * 768 + t] : 0.f;
        xm3 = xm2; xm2 = xm1; xm1 = v;
    }
    #pragma unroll
    for (int ll = 0; ll < 16; ++ll) {
        int l = l0 + ll;
        float v = xz[(size_t)(b * LQ + l) * 768 + t];
        float acc = bias;
        acc = fmaf(w.x, xm3, acc);
        acc = fmaf(w.y, xm2, acc);
        acc = fmaf(w.z, xm1, acc);
        acc = fmaf(w.w, v, acc);
        float rr = acc / (1.f + __expf(-acc));
        x_conv[(size_t)(b * LQ + l) * DINNER + t] = rr;
        cs[ll * DINNER + t] = rr;
        xm3 = xm2; xm2 = xm1; xm1 = v;
    }
    __syncthreads();
    float* dst = x_convT + ((size_t)(b * DINNER) + t) * LQ + l0;
    #pragma unroll
    for (int q = 0; q < 16; q += 4) {
        float4 v = make_float4(cs[(q+0) * DINNER + t], cs[(q+1) * DINNER + t],
                               cs[(q+2) * DINNER + t], cs[(q+3) * DINNER + t]);
        *(float4*)(dst + q) = v;
    }
}

// ---------------- K3: x_dbl partials (split-K=4): p[ds][b,l,48] ---------------------
__global__ __launch_bounds__(256) void k3_xdbl(const float* __restrict__ x_convT,
                                               const float* __restrict__ WxT,
                                               float* __restrict__ xdp) {
    int b = blockIdx.z, ds = blockIdx.y, lb = blockIdx.x;
    int t = threadIdx.x;
    int lane = t & 63;
    int kg = __builtin_amdgcn_readfirstlane(t >> 6);
    int k0 = kg * 12;
    int l = lb * 64 + lane;
    const float* src = x_convT + (size_t)(b * DINNER + ds * 96) * LQ + l;
    float acc[12];
    #pragma unroll
    for (int i = 0; i < 12; ++i) acc[i] = 0.f;
    #pragma unroll 4
    for (int d = 0; d < 96; ++d) {
        float xv = src[(size_t)d * LQ];
        const float* Wr = WxT + (size_t)(ds * 96 + d) * XDBLP + k0;  // uniform
        #pragma unroll
        for (int i = 0; i < 12; ++i) acc[i] = fmaf(xv, Wr[i], acc[i]);
    }
    float* dst = xdp + (size_t)ds * (BQ * LQ * XDBLP) + (size_t)(b * LQ + l) * XDBLP + k0;
    #pragma unroll
    for (int i = 0; i < 12; i += 4)
        *(float4*)(dst + i) = make_float4(acc[i], acc[i+1], acc[i+2], acc[i+3]);
}

// ---------------- K5: scan pass A — local scan; emit hend, sumd, y_part, sdc --------
// grid (256 ch, 2 b), block 384 (thread = d).
__global__ __launch_bounds__(DINNER) void k5_scanA(const float* __restrict__ x_conv,
                                                   const float* __restrict__ xdp,
                                                   const float* __restrict__ W_dt,
                                                   const float* __restrict__ b_dt,
                                                   const float* __restrict__ A_log,
                                                   float* __restrict__ hend,
                                                   float* __restrict__ sumd,
                                                   float* __restrict__ ypart,
                                                   float* __restrict__ sdc) {
    __shared__ float xd[CS * XDBLP];   // 3 KB: dt|B|C rows for this chunk
    int b = blockIdx.y, ch = blockIdx.x;
    int l0 = ch * CS;
    int t = threadIdx.x;
    const size_t PD = (size_t)BQ * LQ * XDBLP;
    size_t base = (size_t)(b * LQ + l0) * XDBLP;
    for (int idx = t; idx < CS * XDBLP; idx += DINNER)
        xd[idx] = xdp[base + idx] + xdp[PD + base + idx]
                + xdp[2 * PD + base + idx] + xdp[3 * PD + base + idx];
    float wdt[12];
    #pragma unroll
    for (int r = 0; r < 12; r += 4) {
        float4 v = *(const float4*)(W_dt + t * 12 + r);
        wdt[r] = v.x; wdt[r+1] = v.y; wdt[r+2] = v.z; wdt[r+3] = v.w;
    }
    float bdt2 = 2.f * b_dt[t];
    float A[NST];
    #pragma unroll
    for (int n = 0; n < NST; ++n) A[n] = -__expf(A_log[t * NST + n]);
    __syncthreads();
    float h[NST];
    #pragma unroll
    for (int n = 0; n < NST; ++n) h[n] = 0.f;
    float sd = 0.f;
    for (int ll = 0; ll < CS; ++ll) {
        size_t gi = (size_t)(b * LQ + l0 + ll) * DINNER + t;
        float u = x_conv[gi];
        float d0 = bdt2, d1 = 0.f, d2 = 0.f;
        #pragma unroll
        for (int r = 0; r < 4; ++r) {
            d0 = fmaf(xd[ll * XDBLP + r], wdt[r], d0);
            d1 = fmaf(xd[ll * XDBLP + 4 + r], wdt[4 + r], d1);
            d2 = fmaf(xd[ll * XDBLP + 8 + r], wdt[8 + r], d2);
        }
        float dr = d0 + d1 + d2;
        float dl = fmaxf(dr, 0.f) + __logf(1.f + __expf(-fabsf(dr)));   // softplus
        sd += dl;
        sdc[gi] = sd;
        float du = dl * u;
        float yv = 0.f;
        #pragma unroll
        for (int n = 0; n < NST; ++n) {
            h[n] = fmaf(__expf(dl * A[n]), h[n], du * xd[ll * XDBLP + 12 + n]);
            yv = fmaf(h[n], xd[ll * XDBLP + 28 + n], yv);
        }
        ypart[gi] = yv;
    }
    size_t hb = ((size_t)(b * NCHUNK + ch) * DINNER + t) * NST;
    #pragma unroll
    for (int n = 0; n < NST; n += 4)
        *(float4*)(hend + hb + n) = make_float4(h[n], h[n+1], h[n+2], h[n+3]);
    sumd[(size_t)(b * NCHUNK + ch) * DINNER + t] = sd;
}

// ---------------- K6: chunk-carry combine, 16 segments x 16 chunks ------------------
// grid (384 d, 2 b), block 256 = 16 n x 16 segments.
__global__ __launch_bounds__(256) void k6_combine(const float* __restrict__ A_log,
                                                  const float* __restrict__ sumd,
                                                  const float* __restrict__ hend,
                                                  float* __restrict__ hin) {
    __shared__ float As[16][NST], Bs[16][NST];
    int d = blockIdx.x, b = blockIdx.y;
    int t = threadIdx.x;
    int n = t & 15, g = t >> 4;
    float A = -__expf(A_log[d * NST + n]);
    float ca = 1.f, cb = 0.f;
    #pragma unroll
    for (int i = 0; i < 16; ++i) {
        int ch = g * 16 + i;
        float a = __expf(A * sumd[(size_t)(b * NCHUNK + ch) * DINNER + d]);
        float bh = hend[((size_t)(b * NCHUNK + ch) * DINNER + d) * NST + n];
        ca *= a;
        cb = fmaf(a, cb, bh);
    }
    As[g][n] = ca; Bs[g][n] = cb;
    __syncthreads();
    float carry = 0.f;                       // h0 = 0
    for (int j = 0; j < g; ++j) carry = fmaf(As[j][n], carry, Bs[j][n]);
    #pragma unroll
    for (int i = 0; i < 16; ++i) {
        int ch = g * 16 + i;
        size_t idx = ((size_t)(b * NCHUNK + ch) * DINNER + d) * NST + n;
        hin[idx] = carry;
        float a = __expf(A * sumd[(size_t)(b * NCHUNK + ch) * DINNER + d]);
        carry = fmaf(a, carry, hend[idx]);
    }
}

// ---------------- K7: pass C — PARALLEL correction + gate, emit yT[b,d,l] -----------
// y = ypart + sum_n exp(A[n]*sdc)*carry[n]*C[l,n]; then +u*D, *silu(z).
// grid (256 ch, 2 b), block 384.
__global__ __launch_bounds__(DINNER) void k7_passC(const float* __restrict__ x_conv,
                                                   const float* __restrict__ xdp,
                                                   const float* __restrict__ A_log,
                                                   const float* __restrict__ hin,
                                                   const float* __restrict__ Dp,
                                                   const float* __restrict__ xz,
                                                   const float* __restrict__ ypart,
                                                   const float* __restrict__ sdc,
                                                   float* __restrict__ yT) {
    __shared__ float cxd[CS * NST];        // C rows, 1 KB
    __shared__ float ys[CS * DINNER];      // 24.6 KB
    int b = blockIdx.y, ch = blockIdx.x;
    int l0 = ch * CS;
    int t = threadIdx.x;
    const size_t PD = (size_t)BQ * LQ * XDBLP;
    for (int idx = t; idx < CS * NST; idx += DINNER) {
        int ll = idx >> 4, n = idx & 15;
        size_t r = (size_t)(b * LQ + l0 + ll) * XDBLP + 28 + n;
        cxd[idx] = xdp[r] + xdp[PD + r] + xdp[2 * PD + r] + xdp[3 * PD + r];
    }
    float A[NST];
    #pragma unroll
    for (int n = 0; n < NST; ++n) A[n] = -__expf(A_log[t * NST + n]);
    float carry[NST];
    size_t hb = ((size_t)(b * NCHUNK + ch) * DINNER + t) * NST;
    #pragma unroll
    for (int n = 0; n < NST; n += 4) {
        float4 v = *(const float4*)(hin + hb + n);
        carry[n] = v.x; carry[n+1] = v.y; carry[n+2] = v.z; carry[n+3] = v.w;
    }
    float Dd = Dp[t];
    __syncthreads();
    #pragma unroll 4
    for (int ll = 0; ll < CS; ++ll) {
        size_t gi = (size_t)(b * LQ + l0 + ll) * DINNER + t;
        size_t zr = (size_t)(b * LQ + l0 + ll) * 768 + 384 + t;
        float yv = ypart[gi];
        float sc = sdc[gi];
        float u  = x_conv[gi];
        float z  = xz[zr];
        #pragma unroll
        for (int n = 0; n < NST; ++n)
            yv = fmaf(__expf(A[n] * sc) * carry[n], cxd[ll * NST + n], yv);
        yv = fmaf(u, Dd, yv);
        float sig = 1.f / (1.f + __expf(-z));
        ys[ll * DINNER + t] = yv * (z * sig);
    }
    __syncthreads();
    float* dst = yT + ((size_t)(b * DINNER) + t) * LQ + l0;
    #pragma unroll
    for (int q = 0; q < CS; q += 4) {
        float4 v = make_float4(ys[(q+0) * DINNER + t], ys[(q+1) * DINNER + t],
                               ys[(q+2) * DINNER + t], ys[(q+3) * DINNER + t]);
        *(float4*)(dst + q) = v;
    }
}

// ---------------- K8: out partials — lanes=c, weights vector, LDS y-tile ------------
// grid (256 lt, 2 ds, 2 b), block 256 = 4 waves. Wave: 64 lanes x 3 c-regs = 192 c,
// own l-quad. Split-K=2 over d (192 each).
__global__ __launch_bounds__(256) void k8_out(const float* __restrict__ yT,
                                              const float* __restrict__ WoutT,
                                              float* __restrict__ op0,
                                              float* __restrict__ op1) {
    __shared__ float yt[DIMC * 17];   // 3264 floats: phase1/2 as [d][ll] (192x16), phase3 as [c*17+ll]
    int lt = blockIdx.x, ds = blockIdx.y, b = blockIdx.z;
    int l0 = lt * 16;
    int t = threadIdx.x;
    const float* yb = yT + (size_t)(b * DINNER + ds * 192) * LQ + l0;
    #pragma unroll
    for (int it = 0; it < 12; ++it) {
        int e = it * 256 + t;                // 3072 = 192*16
        int d = e >> 4, ll = e & 15;
        yt[e] = yb[(size_t)d * LQ + ll];
    }
    __syncthreads();
    int lane = t & 63;
    int lp = __builtin_amdgcn_readfirstlane(t >> 6);   // wave's l-quad
    float acc[3][4];
    #pragma unroll
    for (int k = 0; k < 3; ++k)
        #pragma unroll
        for (int j = 0; j < 4; ++j) acc[k][j] = 0.f;
    const float* Wb = WoutT + (size_t)(ds * 192) * DIMC + lane;
    #pragma unroll 4
    for (int d = 0; d < 192; ++d) {
        float4 yq = *(const float4*)(yt + d * 16 + lp * 4);   // uniform broadcast
        float w0 = Wb[(size_t)d * DIMC];
        float w1 = Wb[(size_t)d * DIMC + 64];
        float w2 = Wb[(size_t)d * DIMC + 128];
        acc[0][0] = fmaf(w0, yq.x, acc[0][0]); acc[0][1] = fmaf(w0, yq.y, acc[0][1]);
        acc[0][2] = fmaf(w0, yq.z, acc[0][2]); acc[0][3] = fmaf(w0, yq.w, acc[0][3]);
        acc[1][0] = fmaf(w1, yq.x, acc[1][0]); acc[1][1] = fmaf(w1, yq.y, acc[1][1]);
        acc[1][2] = fmaf(w1, yq.z, acc[1][2]); acc[1][3] = fmaf(w1, yq.w, acc[1][3]);
        acc[2][0] = fmaf(w2, yq.x, acc[2][0]); acc[2][1] = fmaf(w2, yq.y, acc[2][1]);
        acc[2][2] = fmaf(w2, yq.z, acc[2][2]); acc[2][3] = fmaf(w2, yq.w, acc[2][3]);
    }
    __syncthreads();   // done reading phase-1 layout
    #pragma unroll
    for (int k = 0; k < 3; ++k)
        #pragma unroll
        for (int j = 0; j < 4; ++j)
            yt[(lane + 64 * k) * 17 + lp * 4 + j] = acc[k][j];   // stride-17: conflict-free
    __syncthreads();
    float* op = ds ? op1 : op0;
    #pragma unroll
    for (int it = 0; it < 12; ++it) {
        int e = it * 256 + t;                // 3072 = 192 c x 16 l
        int c = e >> 4, ll = e & 15;
        op[((size_t)b * DIMC + c) * LQ + l0 + ll] = yt[c * 17 + ll];
    }
}

// ---------------- K9: out = op0 + op1 ----------------------------------------------
__global__ __launch_bounds__(256) void k9_sum(const float* __restrict__ op0,
                                              const float* __restrict__ op1,
                                              float* __restrict__ out) {
    size_t i = ((size_t)blockIdx.x * 256 + threadIdx.x) * 4;
    float4 a = *(const float4*)(op0 + i);
    float4 c = *(const float4*)(op1 + i);
    *(float4*)(out + i) = make_float4(a.x + c.x, a.y + c.y, a.z + c.z, a.w + c.w);
}

extern "C" void kernel_launch(void* const* d_in, const int* in_sizes, int n_in,
                              void* d_out, int out_size, void* d_ws, size_t ws_size,
                              hipStream_t stream) {
    const float* x      = (const float*)d_in[0];
    const float* W_in   = (const float*)d_in[1];
    const float* conv_w = (const float*)d_in[2];
    const float* conv_b = (const float*)d_in[3];
    const float* W_x    = (const float*)d_in[4];
    const float* W_dt   = (const float*)d_in[5];
    const float* b_dt   = (const float*)d_in[6];
    const float* A_log  = (const float*)d_in[7];
    const float* Dp     = (const float*)d_in[8];
    const float* W_out  = (const float*)d_in[9];
    float* out = (float*)d_out;

    const size_t NBL = (size_t)BQ * LQ * DINNER;     // 3,145,728
    float* w = (float*)d_ws;
    float* xz      = w; w += (size_t)BQ * LQ * 768;  // 6,291,456
    float* x_conv  = w; w += NBL;
    float* x_convT = w; w += NBL;                    // reused as yT after k3
    float* xdp     = w; w += 4 * (size_t)BQ * LQ * XDBLP;
    float* hend    = w; w += (size_t)BQ * NCHUNK * DINNER * NST;
    float* hin     = w; w += (size_t)BQ * NCHUNK * DINNER * NST;
    float* sumd    = w; w += (size_t)BQ * NCHUNK * DINNER;
    float* ypart   = w; w += NBL;
    float* sdcb    = w; w += NBL;
    float* op0     = w; w += (size_t)BQ * DIMC * LQ;
    float* op1     = w; w += (size_t)BQ * DIMC * LQ;
    float* WxT     = w; w += (size_t)DINNER * XDBLP;
    float* WoutT   = w; w += (size_t)DINNER * DIMC;
    float* yT = x_convT;   // x_convT dead after k3

    k0_transpose<<<288, 256, 0, stream>>>(W_x, W_out, WxT, WoutT);
    k1_inproj<<<dim3(256, 3, BQ), 256, 0, stream>>>(x, W_in, xz);
    k2_conv<<<dim3(256, BQ), 384, 0, stream>>>(xz, conv_w, conv_b, x_conv, x_convT);
    k3_xdbl<<<dim3(64, 4, BQ), 256, 0, stream>>>(x_convT, WxT, xdp);
    k5_scanA<<<dim3(NCHUNK, BQ), DINNER, 0, stream>>>(x_conv, xdp, W_dt, b_dt, A_log,
                                                      hend, sumd, ypart, sdcb);
    k6_combine<<<dim3(DINNER, BQ), 256, 0, stream>>>(A_log, sumd, hend, hin);
    k7_passC<<<dim3(NCHUNK, BQ), DINNER, 0, stream>>>(x_conv, xdp, A_log, hin, Dp,
                                                      xz, ypart, sdcb, yT);
    k8_out<<<dim3(256, 2, BQ), 256, 0, stream>>>(yT, WoutT, op0, op1);
    k9_sum<<<(BQ * DIMC * LQ) / 1024, 256, 0, stream>>>(op0, op1, out);
}

// Round 6
// 216.584 us; speedup vs baseline: 1.4677x; 1.0586x over previous
//
#include <hip/hip_runtime.h>

#define BQ 2
#define DIMC 192
#define DINNER 384
#define LQ 4096
#define NST 16
#define XDBLP 48
#define NCHUNK 256
#define CS 16   // LQ / NCHUNK

// ---------------- K0: transpose weights (W_x -> 384x48 padded, W_out -> 384x192) ----
__global__ void k0_transpose(const float* __restrict__ Wx, const float* __restrict__ Wout,
                             float* __restrict__ WxT, float* __restrict__ WoutT) {
    int t = blockIdx.x * 256 + threadIdx.x;
    if (t < DINNER * XDBLP) {
        int d = t / XDBLP, k = t % XDBLP;
        WxT[t] = (k < 44) ? Wx[k * DINNER + d] : 0.f;
    }
    if (t < DINNER * DIMC) {
        int d = t / DIMC, c = t % DIMC;
        WoutT[t] = Wout[c * DINNER + d];
    }
}

// ---------------- K1: xz = xf @ W_in — lane owns m-quad, wave owns l-octet ----------
// grid (128 lb, 3 mb, 2 b), block 256 = 4 waves. Tile 32 l x 256 m.
// Per c: 1 global_load_dwordx4 (weights) + 2 uniform ds_read_b128 (x) + 32 FMA.
__global__ __launch_bounds__(256) void k1_inproj(const float* __restrict__ x,
                                                 const float* __restrict__ W_in,
                                                 float* __restrict__ xz) {
    __shared__ float xs[DIMC * 32];   // 24 KB, [c][ll]
    int b = blockIdx.z, lb = blockIdx.x, mb = blockIdx.y;
    int t = threadIdx.x;
    int l0 = lb * 32;
    const float* xb = x + (size_t)b * DIMC * LQ + l0;
    #pragma unroll
    for (int it = 0; it < 24; ++it) {
        int e = it * 256 + t;                // 6144 = 192*32
        int c = e >> 5, ll = e & 31;
        xs[e] = xb[(size_t)c * LQ + ll];     // 128B segments
    }
    __syncthreads();
    int lane = t & 63;
    int wq = __builtin_amdgcn_readfirstlane(t >> 6);   // wave's l-octet
    int m0 = mb * 256 + lane * 4;
    float4 acc[8];
    #pragma unroll
    for (int j = 0; j < 8; ++j) acc[j] = make_float4(0.f, 0.f, 0.f, 0.f);
    const float* Wb = W_in + m0;
    #pragma unroll 4
    for (int c = 0; c < DIMC; ++c) {
        float4 wv = *(const float4*)(Wb + (size_t)c * 768);         // coalesced 1KB/wave
        float4 xa = *(const float4*)(xs + c * 32 + wq * 8);         // uniform broadcast
        float4 xc = *(const float4*)(xs + c * 32 + wq * 8 + 4);
        #define K1FMA(J, XV) \
            acc[J].x = fmaf(wv.x, XV, acc[J].x); acc[J].y = fmaf(wv.y, XV, acc[J].y); \
            acc[J].z = fmaf(wv.z, XV, acc[J].z); acc[J].w = fmaf(wv.w, XV, acc[J].w);
        K1FMA(0, xa.x) K1FMA(1, xa.y) K1FMA(2, xa.z) K1FMA(3, xa.w)
        K1FMA(4, xc.x) K1FMA(5, xc.y) K1FMA(6, xc.z) K1FMA(7, xc.w)
        #undef K1FMA
    }
    #pragma unroll
    for (int j = 0; j < 8; ++j)
        *(float4*)(xz + (size_t)(b * LQ + l0 + wq * 8 + j) * 768 + m0) = acc[j];
}

// ---------------- K2: causal conv(4)+silu -> x_conv [b,l,d] AND x_convT [b,d,l] -----
// grid (256 lb, 2 b), block 384 (thread = d). Sliding window over 16-l tile.
__global__ __launch_bounds__(384) void k2_conv(const float* __restrict__ xz,
                                               const float* __restrict__ conv_w,
                                               const float* __restrict__ conv_b,
                                               float* __restrict__ x_conv,
                                               float* __restrict__ x_convT) {
    __shared__ float cs[16 * DINNER];   // 24.6 KB
    int b = blockIdx.y, lb = blockIdx.x;
    int l0 = lb * 16;
    int t = threadIdx.x;   // = d
    float4 w = *(const float4*)(conv_w + t * 4);
    float bias = conv_b[t];
    float xm3 = 0.f, xm2 = 0.f, xm1 = 0.f;
    #pragma unroll
    for (int i = 3; i >= 1; --i) {
        int l = l0 - i;
        float v = (l >= 0) ? xz[(size_t)(b * LQ + l) * 768 + t] : 0.f;
        xm3 = xm2; xm2 = xm1; xm1 = v;
    }
    #pragma unroll
    for (int ll = 0; ll < 16; ++ll) {
        int l = l0 + ll;
        float v = xz[(size_t)(b * LQ + l) * 768 + t];
        float acc = bias;
        acc = fmaf(w.x, xm3, acc);
        acc = fmaf(w.y, xm2, acc);
        acc = fmaf(w.z, xm1, acc);
        acc = fmaf(w.w, v, acc);
        float rr = acc / (1.f + __expf(-acc));
        x_conv[(size_t)(b * LQ + l) * DINNER + t] = rr;
        cs[ll * DINNER + t] = rr;
        xm3 = xm2; xm2 = xm1; xm1 = v;
    }
    __syncthreads();
    float* dst = x_convT + ((size_t)(b * DINNER) + t) * LQ + l0;
    #pragma unroll
    for (int q = 0; q < 16; q += 4) {
        float4 v = make_float4(cs[(q+0) * DINNER + t], cs[(q+1) * DINNER + t],
                               cs[(q+2) * DINNER + t], cs[(q+3) * DINNER + t]);
        *(float4*)(dst + q) = v;
    }
}

// ---------------- K3: x_dbl partials (split-K=4): p[ds][b,l,48] ---------------------
__global__ __launch_bounds__(256) void k3_xdbl(const float* __restrict__ x_convT,
                                               const float* __restrict__ WxT,
                                               float* __restrict__ xdp) {
    int b = blockIdx.z, ds = blockIdx.y, lb = blockIdx.x;
    int t = threadIdx.x;
    int lane = t & 63;
    int kg = __builtin_amdgcn_readfirstlane(t >> 6);
    int k0 = kg * 12;
    int l = lb * 64 + lane;
    const float* src = x_convT + (size_t)(b * DINNER + ds * 96) * LQ + l;
    float acc[12];
    #pragma unroll
    for (int i = 0; i < 12; ++i) acc[i] = 0.f;
    #pragma unroll 4
    for (int d = 0; d < 96; ++d) {
        float xv = src[(size_t)d * LQ];
        const float* Wr = WxT + (size_t)(ds * 96 + d) * XDBLP + k0;  // uniform
        #pragma unroll
        for (int i = 0; i < 12; ++i) acc[i] = fmaf(xv, Wr[i], acc[i]);
    }
    float* dst = xdp + (size_t)ds * (BQ * LQ * XDBLP) + (size_t)(b * LQ + l) * XDBLP + k0;
    #pragma unroll
    for (int i = 0; i < 12; i += 4)
        *(float4*)(dst + i) = make_float4(acc[i], acc[i+1], acc[i+2], acc[i+3]);
}

// ---------------- K5: scan pass A — local scan; emit hend, sumd, y_part, sdc --------
// grid (256 ch, 2 b), block 384 (thread = d).
__global__ __launch_bounds__(DINNER) void k5_scanA(const float* __restrict__ x_conv,
                                                   const float* __restrict__ xdp,
                                                   const float* __restrict__ W_dt,
                                                   const float* __restrict__ b_dt,
                                                   const float* __restrict__ A_log,
                                                   float* __restrict__ hend,
                                                   float* __restrict__ sumd,
                                                   float* __restrict__ ypart,
                                                   float* __restrict__ sdc) {
    __shared__ float xd[CS * XDBLP];   // 3 KB: dt|B|C rows for this chunk
    int b = blockIdx.y, ch = blockIdx.x;
    int l0 = ch * CS;
    int t = threadIdx.x;
    const size_t PD = (size_t)BQ * LQ * XDBLP;
    size_t base = (size_t)(b * LQ + l0) * XDBLP;
    for (int idx = t; idx < CS * XDBLP; idx += DINNER)
        xd[idx] = xdp[base + idx] + xdp[PD + base + idx]
                + xdp[2 * PD + base + idx] + xdp[3 * PD + base + idx];
    float wdt[12];
    #pragma unroll
    for (int r = 0; r < 12; r += 4) {
        float4 v = *(const float4*)(W_dt + t * 12 + r);
        wdt[r] = v.x; wdt[r+1] = v.y; wdt[r+2] = v.z; wdt[r+3] = v.w;
    }
    float bdt2 = 2.f * b_dt[t];
    float A[NST];
    #pragma unroll
    for (int n = 0; n < NST; ++n) A[n] = -__expf(A_log[t * NST + n]);
    __syncthreads();
    float h[NST];
    #pragma unroll
    for (int n = 0; n < NST; ++n) h[n] = 0.f;
    float sd = 0.f;
    for (int ll = 0; ll < CS; ++ll) {
        size_t gi = (size_t)(b * LQ + l0 + ll) * DINNER + t;
        float u = x_conv[gi];
        float d0 = bdt2, d1 = 0.f, d2 = 0.f;
        #pragma unroll
        for (int r = 0; r < 4; ++r) {
            d0 = fmaf(xd[ll * XDBLP + r], wdt[r], d0);
            d1 = fmaf(xd[ll * XDBLP + 4 + r], wdt[4 + r], d1);
            d2 = fmaf(xd[ll * XDBLP + 8 + r], wdt[8 + r], d2);
        }
        float dr = d0 + d1 + d2;
        float dl = fmaxf(dr, 0.f) + __logf(1.f + __expf(-fabsf(dr)));   // softplus
        sd += dl;
        sdc[gi] = sd;
        float du = dl * u;
        float yv = 0.f;
        #pragma unroll
        for (int n = 0; n < NST; ++n) {
            h[n] = fmaf(__expf(dl * A[n]), h[n], du * xd[ll * XDBLP + 12 + n]);
            yv = fmaf(h[n], xd[ll * XDBLP + 28 + n], yv);
        }
        ypart[gi] = yv;
    }
    size_t hb = ((size_t)(b * NCHUNK + ch) * DINNER + t) * NST;
    #pragma unroll
    for (int n = 0; n < NST; n += 4)
        *(float4*)(hend + hb + n) = make_float4(h[n], h[n+1], h[n+2], h[n+3]);
    sumd[(size_t)(b * NCHUNK + ch) * DINNER + t] = sd;
}

// ---------------- K6: chunk-carry combine, 16 segments x 16 chunks ------------------
// grid (384 d, 2 b), block 256 = 16 n x 16 segments.
__global__ __launch_bounds__(256) void k6_combine(const float* __restrict__ A_log,
                                                  const float* __restrict__ sumd,
                                                  const float* __restrict__ hend,
                                                  float* __restrict__ hin) {
    __shared__ float As[16][NST], Bs[16][NST];
    int d = blockIdx.x, b = blockIdx.y;
    int t = threadIdx.x;
    int n = t & 15, g = t >> 4;
    float A = -__expf(A_log[d * NST + n]);
    float ca = 1.f, cb = 0.f;
    #pragma unroll
    for (int i = 0; i < 16; ++i) {
        int ch = g * 16 + i;
        float a = __expf(A * sumd[(size_t)(b * NCHUNK + ch) * DINNER + d]);
        float bh = hend[((size_t)(b * NCHUNK + ch) * DINNER + d) * NST + n];
        ca *= a;
        cb = fmaf(a, cb, bh);
    }
    As[g][n] = ca; Bs[g][n] = cb;
    __syncthreads();
    float carry = 0.f;                       // h0 = 0
    for (int j = 0; j < g; ++j) carry = fmaf(As[j][n], carry, Bs[j][n]);
    #pragma unroll
    for (int i = 0; i < 16; ++i) {
        int ch = g * 16 + i;
        size_t idx = ((size_t)(b * NCHUNK + ch) * DINNER + d) * NST + n;
        hin[idx] = carry;
        float a = __expf(A * sumd[(size_t)(b * NCHUNK + ch) * DINNER + d]);
        carry = fmaf(a, carry, hend[idx]);
    }
}

// ---------------- K7: pass C — PARALLEL correction + gate, emit yT[b,d,l] -----------
// grid (256 ch, 2 b), block 384.
__global__ __launch_bounds__(DINNER) void k7_passC(const float* __restrict__ x_conv,
                                                   const float* __restrict__ xdp,
                                                   const float* __restrict__ A_log,
                                                   const float* __restrict__ hin,
                                                   const float* __restrict__ Dp,
                                                   const float* __restrict__ xz,
                                                   const float* __restrict__ ypart,
                                                   const float* __restrict__ sdc,
                                                   float* __restrict__ yT) {
    __shared__ float cxd[CS * NST];        // C rows, 1 KB
    __shared__ float ys[CS * DINNER];      // 24.6 KB
    int b = blockIdx.y, ch = blockIdx.x;
    int l0 = ch * CS;
    int t = threadIdx.x;
    const size_t PD = (size_t)BQ * LQ * XDBLP;
    for (int idx = t; idx < CS * NST; idx += DINNER) {
        int ll = idx >> 4, n = idx & 15;
        size_t r = (size_t)(b * LQ + l0 + ll) * XDBLP + 28 + n;
        cxd[idx] = xdp[r] + xdp[PD + r] + xdp[2 * PD + r] + xdp[3 * PD + r];
    }
    float A[NST];
    #pragma unroll
    for (int n = 0; n < NST; ++n) A[n] = -__expf(A_log[t * NST + n]);
    float carry[NST];
    size_t hb = ((size_t)(b * NCHUNK + ch) * DINNER + t) * NST;
    #pragma unroll
    for (int n = 0; n < NST; n += 4) {
        float4 v = *(const float4*)(hin + hb + n);
        carry[n] = v.x; carry[n+1] = v.y; carry[n+2] = v.z; carry[n+3] = v.w;
    }
    float Dd = Dp[t];
    __syncthreads();
    #pragma unroll 4
    for (int ll = 0; ll < CS; ++ll) {
        size_t gi = (size_t)(b * LQ + l0 + ll) * DINNER + t;
        size_t zr = (size_t)(b * LQ + l0 + ll) * 768 + 384 + t;
        float yv = ypart[gi];
        float sc = sdc[gi];
        float u  = x_conv[gi];
        float z  = xz[zr];
        #pragma unroll
        for (int n = 0; n < NST; ++n)
            yv = fmaf(__expf(A[n] * sc) * carry[n], cxd[ll * NST + n], yv);
        yv = fmaf(u, Dd, yv);
        float sig = 1.f / (1.f + __expf(-z));
        ys[ll * DINNER + t] = yv * (z * sig);
    }
    __syncthreads();
    float* dst = yT + ((size_t)(b * DINNER) + t) * LQ + l0;
    #pragma unroll
    for (int q = 0; q < CS; q += 4) {
        float4 v = make_float4(ys[(q+0) * DINNER + t], ys[(q+1) * DINNER + t],
                               ys[(q+2) * DINNER + t], ys[(q+3) * DINNER + t]);
        *(float4*)(dst + q) = v;
    }
}

// ---------------- K8: out partials — 32-l tile, wave owns l-octet -------------------
// grid (128 lt, 2 ds, 2 b), block 256. Lane: c = lane + {0,64,128}. Split-K=2 over d.
__global__ __launch_bounds__(256) void k8_out(const float* __restrict__ yT,
                                              const float* __restrict__ WoutT,
                                              float* __restrict__ op0,
                                              float* __restrict__ op1) {
    __shared__ float yt[DIMC * 33];   // 25.3 KB; stage as [d][ll] (192x32), transpose as [c*33+ll]
    int lt = blockIdx.x, ds = blockIdx.y, b = blockIdx.z;
    int l0 = lt * 32;
    int t = threadIdx.x;
    const float* yb = yT + (size_t)(b * DINNER + ds * 192) * LQ + l0;
    #pragma unroll
    for (int it = 0; it < 24; ++it) {
        int e = it * 256 + t;                // 6144 = 192*32
        int d = e >> 5, ll = e & 31;
        yt[d * 32 + ll] = yb[(size_t)d * LQ + ll];
    }
    __syncthreads();
    int lane = t & 63;
    int wq = __builtin_amdgcn_readfirstlane(t >> 6);   // wave's l-octet
    float acc[8][3];
    #pragma unroll
    for (int j = 0; j < 8; ++j)
        #pragma unroll
        for (int k = 0; k < 3; ++k) acc[j][k] = 0.f;
    const float* Wb = WoutT + (size_t)(ds * 192) * DIMC + lane;
    #pragma unroll 4
    for (int d = 0; d < 192; ++d) {
        float4 ya = *(const float4*)(yt + d * 32 + wq * 8);       // uniform broadcast
        float4 yc = *(const float4*)(yt + d * 32 + wq * 8 + 4);
        float w0 = Wb[(size_t)d * DIMC];
        float w1 = Wb[(size_t)d * DIMC + 64];
        float w2 = Wb[(size_t)d * DIMC + 128];
        acc[0][0] = fmaf(w0, ya.x, acc[0][0]); acc[0][1] = fmaf(w1, ya.x, acc[0][1]); acc[0][2] = fmaf(w2, ya.x, acc[0][2]);
        acc[1][0] = fmaf(w0, ya.y, acc[1][0]); acc[1][1] = fmaf(w1, ya.y, acc[1][1]); acc[1][2] = fmaf(w2, ya.y, acc[1][2]);
        acc[2][0] = fmaf(w0, ya.z, acc[2][0]); acc[2][1] = fmaf(w1, ya.z, acc[2][1]); acc[2][2] = fmaf(w2, ya.z, acc[2][2]);
        acc[3][0] = fmaf(w0, ya.w, acc[3][0]); acc[3][1] = fmaf(w1, ya.w, acc[3][1]); acc[3][2] = fmaf(w2, ya.w, acc[3][2]);
        acc[4][0] = fmaf(w0, yc.x, acc[4][0]); acc[4][1] = fmaf(w1, yc.x, acc[4][1]); acc[4][2] = fmaf(w2, yc.x, acc[4][2]);
        acc[5][0] = fmaf(w0, yc.y, acc[5][0]); acc[5][1] = fmaf(w1, yc.y, acc[5][1]); acc[5][2] = fmaf(w2, yc.y, acc[5][2]);
        acc[6][0] = fmaf(w0, yc.z, acc[6][0]); acc[6][1] = fmaf(w1, yc.z, acc[6][1]); acc[6][2] = fmaf(w2, yc.z, acc[6][2]);
        acc[7][0] = fmaf(w0, yc.w, acc[7][0]); acc[7][1] = fmaf(w1, yc.w, acc[7][1]); acc[7][2] = fmaf(w2, yc.w, acc[7][2]);
    }
    __syncthreads();   // done reading stage layout
    #pragma unroll
    for (int k = 0; k < 3; ++k)
        #pragma unroll
        for (int j = 0; j < 8; ++j)
            yt[(lane + 64 * k) * 33 + wq * 8 + j] = acc[j][k];   // stride-33: conflict-free
    __syncthreads();
    float* op = ds ? op1 : op0;
    #pragma unroll
    for (int it = 0; it < 24; ++it) {
        int e = it * 256 + t;                // 6144 = 192 c x 32 l
        int c = e >> 5, ll = e & 31;
        op[((size_t)b * DIMC + c) * LQ + l0 + ll] = yt[c * 33 + ll];
    }
}

// ---------------- K9: out = op0 + op1 ----------------------------------------------
__global__ __launch_bounds__(256) void k9_sum(const float* __restrict__ op0,
                                              const float* __restrict__ op1,
                                              float* __restrict__ out) {
    size_t i = ((size_t)blockIdx.x * 256 + threadIdx.x) * 4;
    float4 a = *(const float4*)(op0 + i);
    float4 c = *(const float4*)(op1 + i);
    *(float4*)(out + i) = make_float4(a.x + c.x, a.y + c.y, a.z + c.z, a.w + c.w);
}

extern "C" void kernel_launch(void* const* d_in, const int* in_sizes, int n_in,
                              void* d_out, int out_size, void* d_ws, size_t ws_size,
                              hipStream_t stream) {
    const float* x      = (const float*)d_in[0];
    const float* W_in   = (const float*)d_in[1];
    const float* conv_w = (const float*)d_in[2];
    const float* conv_b = (const float*)d_in[3];
    const float* W_x    = (const float*)d_in[4];
    const float* W_dt   = (const float*)d_in[5];
    const float* b_dt   = (const float*)d_in[6];
    const float* A_log  = (const float*)d_in[7];
    const float* Dp     = (const float*)d_in[8];
    const float* W_out  = (const float*)d_in[9];
    float* out = (float*)d_out;

    const size_t NBL = (size_t)BQ * LQ * DINNER;     // 3,145,728
    float* w = (float*)d_ws;
    float* xz      = w; w += (size_t)BQ * LQ * 768;  // 6,291,456
    float* x_conv  = w; w += NBL;
    float* x_convT = w; w += NBL;                    // reused as yT after k3
    float* xdp     = w; w += 4 * (size_t)BQ * LQ * XDBLP;
    float* hend    = w; w += (size_t)BQ * NCHUNK * DINNER * NST;
    float* hin     = w; w += (size_t)BQ * NCHUNK * DINNER * NST;
    float* sumd    = w; w += (size_t)BQ * NCHUNK * DINNER;
    float* ypart   = w; w += NBL;
    float* sdcb    = w; w += NBL;
    float* op0     = w; w += (size_t)BQ * DIMC * LQ;
    float* op1     = w; w += (size_t)BQ * DIMC * LQ;
    float* WxT     = w; w += (size_t)DINNER * XDBLP;
    float* WoutT   = w; w += (size_t)DINNER * DIMC;
    float* yT = x_convT;   // x_convT dead after k3

    k0_transpose<<<288, 256, 0, stream>>>(W_x, W_out, WxT, WoutT);
    k1_inproj<<<dim3(128, 3, BQ), 256, 0, stream>>>(x, W_in, xz);
    k2_conv<<<dim3(256, BQ), 384, 0, stream>>>(xz, conv_w, conv_b, x_conv, x_convT);
    k3_xdbl<<<dim3(64, 4, BQ), 256, 0, stream>>>(x_convT, WxT, xdp);
    k5_scanA<<<dim3(NCHUNK, BQ), DINNER, 0, stream>>>(x_conv, xdp, W_dt, b_dt, A_log,
                                                      hend, sumd, ypart, sdcb);
    k6_combine<<<dim3(DINNER, BQ), 256, 0, stream>>>(A_log, sumd, hend, hin);
    k7_passC<<<dim3(NCHUNK, BQ), DINNER, 0, stream>>>(x_conv, xdp, A_log, hin, Dp,
                                                      xz, ypart, sdcb, yT);
    k8_out<<<dim3(128, 2, BQ), 256, 0, stream>>>(yT, WoutT, op0, op1);
    k9_sum<<<(BQ * DIMC * LQ) / 1024, 256, 0, stream>>>(op0, op1, out);
}